// Round 11
// baseline (324.758 us; speedup 1.0000x reference)
//
#include <hip/hip_runtime.h>
#include <cmath>

typedef unsigned short u16;
typedef unsigned int   u32;
typedef short bf16x8 __attribute__((ext_vector_type(8)));
typedef float f32x4 __attribute__((ext_vector_type(4)));

// Problem constants
constexpr int B_ = 8, T_ = 32, N_ = 24, D_ = 128;
constexpr int BT_ = B_ * T_;            // 256
constexpr int VW_ = N_ * N_;            // 576
constexpr int BTN_ = BT_ * N_;          // 6144
constexpr int BTVW_ = BT_ * VW_;        // 147456
constexpr int P_ = 3;
constexpr int C_ = 6;
constexpr int SA_ = 136;                // k_fused A row stride (u16); /2=68 u32

__device__ __forceinline__ float bits2f(u32 u) { float f; __builtin_memcpy(&f, &u, 4); return f; }
__device__ __forceinline__ float bf2f(u16 h) { return bits2f(((u32)h) << 16); }
__device__ __forceinline__ u16 f2bf(float f) {
    u32 u; __builtin_memcpy(&u, &f, 4);
    u32 r = u + 0x7FFFu + ((u >> 16) & 1u);
    return (u16)(r >> 16);
}
__device__ __forceinline__ f32x4 ld4bf(const u16* p) {
    const uint2 v = *(const uint2*)p;
    f32x4 r;
    r[0] = bf2f((u16)v.x); r[1] = bf2f((u16)(v.x >> 16));
    r[2] = bf2f((u16)v.y); r[3] = bf2f((u16)(v.y >> 16));
    return r;
}
// Fast activations via hardware v_exp_f32 / v_rcp_f32 (error ~1e-6).
__device__ __forceinline__ float fexp2(float x) { return __builtin_amdgcn_exp2f(x); }
__device__ __forceinline__ float frcp(float x) { return __builtin_amdgcn_rcpf(x); }
__device__ __forceinline__ float sigm(float x) {
    return frcp(1.0f + fexp2(x * -1.4426950408889634f));
}
__device__ __forceinline__ float ftanh(float x) {
    const float t = fexp2(fabsf(x) * -2.8853900817779268f);
    return copysignf((1.0f - t) * frcp(1.0f + t), x);
}

// ---------------------------------------------------------------------------
// Merged preprocessing: node transpose (blocks 0..255) + fragment-linear
// weight repack (blocks 256..1343) + small-array bf16 convert (1344..1355).
// ---------------------------------------------------------------------------
struct PreArgs {
    const float* node; float* HN; u16* HNb;
    const float* fsrc[7]; u16* fdst[7]; int fstart[8];
    const void* csrc[10]; u16* cdst[10]; int cstart[11];
};

__global__ __launch_bounds__(256) void k_preproc(PreArgs a) {
    const int bx = blockIdx.x;
    if (bx < 256) {
        const int bt = bx;
        for (int f = threadIdx.x; f < 3072; f += 256) {
            const int d = f / 24, n = f - d * 24;
            const float v = a.node[(size_t)bt * 3072 + f];
            a.HN[(size_t)bt * 3072 + n * 128 + d] = v;
            a.HNb[(size_t)bt * 3072 + n * 128 + d] = f2bf(v);
        }
    } else if (bx < 1344) {
        // FL[((rb*4+ks)*64 + lane)*8 + e] = W[(rb*16+m)*128 + ks*32 + quad*8 + e]
        const int idx = (bx - 256) * 256 + threadIdx.x;
        if (idx >= a.fstart[7]) return;
        int s = 0;
#pragma unroll
        for (int i = 1; i < 7; ++i) s += (idx >= a.fstart[i]) ? 1 : 0;
        const int off = idx - a.fstart[s];
        const int e = off & 7, lane = (off >> 3) & 63;
        const int ks = (off >> 9) & 3, rb = off >> 11;
        const int m = lane & 15, quad = lane >> 4;
        a.fdst[s][off] = f2bf(a.fsrc[s][(size_t)(rb * 16 + m) * 128 + ks * 32 + quad * 8 + e]);
    } else {
        const int idx = (bx - 1344) * 256 + threadIdx.x;
        if (idx >= a.cstart[10]) return;
        int s = 0;
#pragma unroll
        for (int i = 1; i < 10; ++i) s += (idx >= a.cstart[i]) ? 1 : 0;
        const int off = idx - a.cstart[s];
        a.cdst[s][off] = f2bf(((const float*)a.csrc[s])[off]);
    }
}

// ---------------------------------------------------------------------------
// k_prep: fused edge transpose + ME GEMM + layer-0 link-MLP.
// TWO waves per 32-row tile: both waves stage cooperatively (8 loads/lane),
// then wave0 runs the 8-ct ME pass and wave1 the 8-ct link pass in parallel
// — halves the per-wave serial load->vmcnt->MFMA chain that the allocator
// refuses to pipeline (R7-R10 evidence: VGPR pinned ~56, all mem ops at
// full latency). Same ops, same per-output order -> bit-identical.
// ---------------------------------------------------------------------------
__global__ __launch_bounds__(128) void k_prep(
    const float* __restrict__ edge, const u16* __restrict__ WeF,
    const u16* __restrict__ W1F, const u16* __restrict__ b1,
    const u16* __restrict__ W2, const u16* __restrict__ b2,
    u16* __restrict__ ME, float* __restrict__ ADJ) {
    __shared__ __align__(16) u16 A[32 * 128];   // swizzled, 8 KB
    const int tid = threadIdx.x;                // 0..127
    const int bt = blockIdx.x / 18, tile = blockIdx.x % 18;
    const int vw0 = tile * 32;
    const size_t ebase = (size_t)bt * D_ * VW_ + vw0;
    // ---- staging: 8 float4 loads/lane across 128 threads ----
    const int vq = tid & 7, dg = tid >> 3;      // vq: vw-quad (8), dg: d-pair group (16)
    u32* A32 = (u32*)A;
    {
        float4 fa[4], fb[4];
#pragma unroll
        for (int it = 0; it < 4; ++it) {
            const int d0 = it * 32 + dg * 2;
            fa[it] = *(const float4*)&edge[ebase + (size_t)d0 * VW_ + vq * 4];
            fb[it] = *(const float4*)&edge[ebase + (size_t)(d0 + 1) * VW_ + vq * 4];
        }
#pragma unroll
        for (int it = 0; it < 4; ++it) {
            const int d0 = it * 32 + dg * 2;
            const float* pa = (const float*)&fa[it];
            const float* pb = (const float*)&fb[it];
#pragma unroll
            for (int i = 0; i < 4; ++i) {
                const int row = vq * 4 + i;
                const int sw32 = ((row >> 2) & 7) * 4;
                A32[row * 64 + ((d0 >> 1) ^ sw32)] =
                    (u32)f2bf(pa[i]) | ((u32)f2bf(pb[i]) << 16);
            }
        }
    }
    __syncthreads();
    const int wv = tid >> 6, lane = tid & 63;
    const int m = lane & 15, quad = lane >> 4;
    bf16x8 a[2][4];
#pragma unroll
    for (int rt = 0; rt < 2; ++rt) {
        const int row = rt * 16 + m;
        const int sw16 = ((row >> 2) & 7) * 8;
#pragma unroll
        for (int ks = 0; ks < 4; ++ks)
            a[rt][ks] = *(const bf16x8*)&A[row * 128 + ((ks * 32 + quad * 8) ^ sw16)];
    }
    const f32x4 z = {0.f, 0.f, 0.f, 0.f};
    if (wv == 0) {
        // ---- ME = A @ We^T (swapped operands -> coalesced uint2 stores) ----
#pragma unroll
        for (int ct = 0; ct < 8; ++ct) {
            bf16x8 bw[4];
#pragma unroll
            for (int ks = 0; ks < 4; ++ks)
                bw[ks] = *(const bf16x8*)&WeF[((ct * 4 + ks) << 9) + lane * 8];
            f32x4 acc[2];
#pragma unroll
            for (int rt = 0; rt < 2; ++rt) acc[rt] = z;
#pragma unroll
            for (int rt = 0; rt < 2; ++rt)
#pragma unroll
                for (int ks = 0; ks < 4; ++ks)
                    acc[rt] = __builtin_amdgcn_mfma_f32_16x16x32_bf16(bw[ks], a[rt][ks], acc[rt], 0, 0, 0);
#pragma unroll
            for (int rt = 0; rt < 2; ++rt) {
                const u32 lo = (u32)f2bf(acc[rt][0]) | ((u32)f2bf(acc[rt][1]) << 16);
                const u32 hi = (u32)f2bf(acc[rt][2]) | ((u32)f2bf(acc[rt][3]) << 16);
                *(uint2*)&ME[(size_t)(bt * VW_ + vw0 + rt * 16 + m) * 128 + ct * 16 + quad * 4] =
                    make_uint2(lo, hi);
            }
        }
    } else {
        // ---- layer-0 adjacency: relu(W1@A + b1) . W2 + b2 ----
        float p[2][4] = {};
        const float b2v = bf2f(b2[0]);
#pragma unroll
        for (int ct = 0; ct < 8; ++ct) {
            bf16x8 bw[4];
#pragma unroll
            for (int ks = 0; ks < 4; ++ks)
                bw[ks] = *(const bf16x8*)&W1F[((ct * 4 + ks) << 9) + lane * 8];
            f32x4 acc[2];
#pragma unroll
            for (int rt = 0; rt < 2; ++rt) acc[rt] = z;
#pragma unroll
            for (int rt = 0; rt < 2; ++rt)
#pragma unroll
                for (int ks = 0; ks < 4; ++ks)
                    acc[rt] = __builtin_amdgcn_mfma_f32_16x16x32_bf16(a[rt][ks], bw[ks], acc[rt], 0, 0, 0);
            const int n = ct * 16 + m;
            const float b1v = bf2f(b1[n]);
            const float w2v = bf2f(W2[n]);
#pragma unroll
            for (int rt = 0; rt < 2; ++rt)
#pragma unroll
                for (int reg = 0; reg < 4; ++reg)
                    p[rt][reg] += fmaxf(acc[rt][reg] + b1v, 0.0f) * w2v;
        }
#pragma unroll
        for (int rt = 0; rt < 2; ++rt)
#pragma unroll
            for (int reg = 0; reg < 4; ++reg) {
                float v = p[rt][reg];
                v += __shfl_xor(v, 1);
                v += __shfl_xor(v, 2);
                v += __shfl_xor(v, 4);
                v += __shfl_xor(v, 8);
                p[rt][reg] = v;
            }
        if (m == 0) {
#pragma unroll
            for (int rt = 0; rt < 2; ++rt)
#pragma unroll
                for (int reg = 0; reg < 4; ++reg)
                    ADJ[bt * VW_ + vw0 + rt * 16 + quad * 4 + reg] = p[rt][reg] + b2v;
        }
    }
}

// ---------------------------------------------------------------------------
// Fused per-(bt, v-pair) edge kernel with IN-BLOCK XW recompute (k_xw
// folded in): waves 0-1 compute this bt's 24 XW rows into padded LDS via
// the same MFMA sequence as the old k_xw (bit-identical values), then the
// build phase reads XW from LDS. Kills 3 k_xw launches + XW round trip.
// ---------------------------------------------------------------------------
template <bool ADJP>
__global__ __launch_bounds__(256) void k_fused(
    const u16* __restrict__ ME, const u16* __restrict__ HNb,
    const u16* __restrict__ WhF, const u16* __restrict__ mb,
    const u16* __restrict__ W1F, const u16* __restrict__ b1,
    const u16* __restrict__ W2, const u16* __restrict__ b2,
    const int* __restrict__ nnr, float* __restrict__ ADJ,
    u16* __restrict__ MVb) {
    __shared__ __align__(16) u16 A[48 * SA_];
    __shared__ float gate_s[48];
    __shared__ float2 mvp[2][2][64];
    __shared__ __align__(16) float XWs[24][132];   // padded: 2-way banks max
    const int tid = threadIdx.x;
    const int blk = blockIdx.x;
    const int bt = blk / 12, pr = blk - bt * 12;
    const int v0 = pr * 2;
    const int e0 = bt * VW_ + v0 * N_;
    const int nv = nnr[bt];

    if (tid < 48) gate_s[tid] = sigm(ADJ[e0 + tid]);
    // ---- in-block XW: rows bt*24 .. bt*24+23 (waves 0-1) ----
    {
        const int wv = tid >> 6, lane = tid & 63;
        if (wv < 2) {
            const int m = lane & 15, quad = lane >> 4;
            int rr = bt * 24 + wv * 16 + m;
            if (rr > BTN_ - 1) rr = BTN_ - 1;       // pad rows (unused)
            bf16x8 ah[4];
#pragma unroll
            for (int ks = 0; ks < 4; ++ks)
                ah[ks] = *(const bf16x8*)&HNb[(size_t)rr * 128 + ks * 32 + quad * 8];
            const f32x4 z = {0.f, 0.f, 0.f, 0.f};
            const int lrow = wv * 16 + m;
#pragma unroll
            for (int ct = 0; ct < 8; ++ct) {
                f32x4 acc = z;
#pragma unroll
                for (int ks = 0; ks < 4; ++ks) {
                    const bf16x8 b = *(const bf16x8*)&WhF[((ct * 4 + ks) << 9) + lane * 8];
                    acc = __builtin_amdgcn_mfma_f32_16x16x32_bf16(b, ah[ks], acc, 0, 0, 0);
                }
                if (lrow < 24) *(f32x4*)&XWs[lrow][ct * 16 + quad * 4] = acc;
            }
        }
    }
    __syncthreads();
    {
        const int op = tid & 63;
        const int sub = (tid >> 6) & 1;
        const int grp = tid >> 7;
        const int v = v0 + grp;
        const u32 mbu = ((const u32*)mb)[op];
        const float mb0 = bf2f((u16)mbu), mb1 = bf2f((u16)(mbu >> 16));
        const bool vva = v < nv;
        u32 meR[12];
#pragma unroll
        for (int i = 0; i < 12; ++i) {
            const int w = sub * 12 + i;
            const int rr = grp * 24 + w;
            meR[i] = ((const u32*)ME)[(size_t)(e0 + rr) * 64 + op];
        }
        float mvx = 0.0f, mvy = 0.0f;
        u32* A32 = (u32*)A;
#pragma unroll
        for (int i = 0; i < 12; ++i) {
            const int w = sub * 12 + i;
            const int rr = grp * 24 + w;
            float v0f = 0.0f, v1f = 0.0f;
            if (vva && w < nv) {
                const float g = gate_s[rr];
                const float2 xw = *(const float2*)&XWs[w][2 * op];
                v0f = g * fmaxf(xw.x + bf2f((u16)meR[i]) + mb0, 0.0f);
                v1f = g * fmaxf(xw.y + bf2f((u16)(meR[i] >> 16)) + mb1, 0.0f);
                mvx += v0f; mvy += v1f;
            }
            if (ADJP) A32[rr * 68 + op] = (u32)f2bf(v0f) | ((u32)f2bf(v1f) << 16);
        }
        mvp[grp][sub][op] = make_float2(mvx, mvy);
    }
    __syncthreads();
    if (tid < 128) {
        const int g2 = tid >> 6, o2 = tid & 63;
        const float2 pa = mvp[g2][0][o2], pb = mvp[g2][1][o2];
        ((u32*)MVb)[(size_t)(bt * N_ + v0 + g2) * 64 + o2] =
            (u32)f2bf(pa.x + pb.x) | ((u32)f2bf(pa.y + pb.y) << 16);
    }

    if constexpr (ADJP) {
        __syncthreads();
        if (tid >= 64) return;
        const int m = tid & 15, quad = tid >> 4;
        bf16x8 a[3][4];
#pragma unroll
        for (int rt = 0; rt < 3; ++rt)
#pragma unroll
            for (int ks = 0; ks < 4; ++ks)
                a[rt][ks] = *(const bf16x8*)&A[(rt * 16 + m) * SA_ + ks * 32 + quad * 8];
        const f32x4 z = {0.f, 0.f, 0.f, 0.f};
        float p[3][4] = {};
        const float b2v = bf2f(b2[0]);
#pragma unroll
        for (int ct = 0; ct < 8; ++ct) {
            bf16x8 bw[4];
#pragma unroll
            for (int ks = 0; ks < 4; ++ks)
                bw[ks] = *(const bf16x8*)&W1F[((ct * 4 + ks) << 9) + tid * 8];
            f32x4 acc[3];
#pragma unroll
            for (int rt = 0; rt < 3; ++rt) acc[rt] = z;
#pragma unroll
            for (int rt = 0; rt < 3; ++rt)
#pragma unroll
                for (int ks = 0; ks < 4; ++ks)
                    acc[rt] = __builtin_amdgcn_mfma_f32_16x16x32_bf16(a[rt][ks], bw[ks], acc[rt], 0, 0, 0);
            const int n = ct * 16 + m;
            const float b1v = bf2f(b1[n]);
            const float w2v = bf2f(W2[n]);
#pragma unroll
            for (int rt = 0; rt < 3; ++rt)
#pragma unroll
                for (int reg = 0; reg < 4; ++reg)
                    p[rt][reg] += fmaxf(acc[rt][reg] + b1v, 0.0f) * w2v;
        }
#pragma unroll
        for (int rt = 0; rt < 3; ++rt)
#pragma unroll
            for (int reg = 0; reg < 4; ++reg) {
                float v = p[rt][reg];
                v += __shfl_xor(v, 1);
                v += __shfl_xor(v, 2);
                v += __shfl_xor(v, 4);
                v += __shfl_xor(v, 8);
                p[rt][reg] = v;
            }
        if (m == 0) {
#pragma unroll
            for (int rt = 0; rt < 3; ++rt)
#pragma unroll
                for (int reg = 0; reg < 4; ++reg)
                    ADJ[e0 + rt * 16 + quad * 4 + reg] = p[rt][reg] + b2v;
        }
    }
}

// ---------------------------------------------------------------------------
// Fused MFMA GRU. grid (384,4) x 64: 1 wave = 16 rows x 2 col-tiles.
// ---------------------------------------------------------------------------
__global__ __launch_bounds__(64, 1) void k_gruM(
    const u16* __restrict__ MVb, const u16* __restrict__ HNb_in,
    float* __restrict__ HN, u16* __restrict__ HNb,
    const u16* __restrict__ WihF, const u16* __restrict__ WhhF,
    const u16* __restrict__ bih, const u16* __restrict__ bhh,
    const int* __restrict__ nnr) {
    const int tid = threadIdx.x;
    const int m = tid & 15, quad = tid >> 4;
    const int rbase = blockIdx.x * 16;
    const int ct0 = blockIdx.y * 2;
    bf16x8 amv[4], ahn[4];
#pragma unroll
    for (int ks = 0; ks < 4; ++ks) {
        amv[ks] = *(const bf16x8*)&MVb[(size_t)(rbase + m) * 128 + ks * 32 + quad * 8];
        ahn[ks] = *(const bf16x8*)&HNb_in[(size_t)(rbase + m) * 128 + ks * 32 + quad * 8];
    }
    const int myrow = rbase + m;
    const int mybt = myrow / N_;
    const bool valid = (myrow - mybt * N_) < nnr[mybt];
    const f32x4 z = {0.f, 0.f, 0.f, 0.f};
#pragma unroll
    for (int cti = 0; cti < 2; ++cti) {
        const int ct = ct0 + cti;
        f32x4 gi[3], gh[3];
#pragma unroll
        for (int g = 0; g < 3; ++g) { gi[g] = z; gh[g] = z; }
#pragma unroll
        for (int g = 0; g < 3; ++g) {
            const int rb = g * 8 + ct;
#pragma unroll
            for (int ks = 0; ks < 4; ++ks) {
                const bf16x8 bi_f = *(const bf16x8*)&WihF[((rb * 4 + ks) << 9) + tid * 8];
                const bf16x8 bh_f = *(const bf16x8*)&WhhF[((rb * 4 + ks) << 9) + tid * 8];
                gi[g] = __builtin_amdgcn_mfma_f32_16x16x32_bf16(bi_f, amv[ks], gi[g], 0, 0, 0);
                gh[g] = __builtin_amdgcn_mfma_f32_16x16x32_bf16(bh_f, ahn[ks], gh[g], 0, 0, 0);
            }
        }
        const int col0 = ct * 16 + quad * 4;
        const f32x4 biR = ld4bf(&bih[col0]),       bhR = ld4bf(&bhh[col0]);
        const f32x4 biZ = ld4bf(&bih[128 + col0]), bhZ = ld4bf(&bhh[128 + col0]);
        const f32x4 biN = ld4bf(&bih[256 + col0]), bhN = ld4bf(&bhh[256 + col0]);
        const size_t oi = (size_t)myrow * 128 + col0;
        const f32x4 hold = *(const f32x4*)&HN[oi];
        f32x4 hv;
#pragma unroll
        for (int reg = 0; reg < 4; ++reg) {
            const float r  = sigm(gi[0][reg] + gh[0][reg] + biR[reg] + bhR[reg]);
            const float zz = sigm(gi[1][reg] + gh[1][reg] + biZ[reg] + bhZ[reg]);
            const float nn = ftanh(gi[2][reg] + biN[reg] + r * (gh[2][reg] + bhN[reg]));
            hv[reg] = valid ? ((1.0f - zz) * nn + zz * hold[reg]) : 0.0f;
        }
        *(f32x4*)&HN[oi] = hv;
        const u32 lo = (u32)f2bf(hv[0]) | ((u32)f2bf(hv[1]) << 16);
        const u32 hi = (u32)f2bf(hv[2]) | ((u32)f2bf(hv[3]) << 16);
        *(uint2*)&HNb[oi] = make_uint2(lo, hi);
    }
}

// ---------------------------------------------------------------------------
// GI2 = HNb @ lstm_Wih^T + (bih+bhh) in k_rec's MFMA-lane layout.
// grid (384,8) x 64: 1 wave = 16 rows x 4 col-tiles.
// ---------------------------------------------------------------------------
__global__ __launch_bounds__(64, 2) void k_gi(const u16* __restrict__ HNb,
                                              const u16* __restrict__ WF,
                                              const u16* __restrict__ bih, const u16* __restrict__ bhh,
                                              float* __restrict__ GI2) {
    const int tid = threadIdx.x;
    const int m = tid & 15, quad = tid >> 4;
    const int r0 = blockIdx.x * 16;
    const int ocol0 = blockIdx.y * 64;
    const int r = r0 + m;
    const int btq = r / 24, n = r - btq * 24;
    const int b = btq >> 5, t = btq & 31;
    const int q = b * 24 + n;
    const int blk = q >> 4, mrow = q & 15;
    bf16x8 a[4];
#pragma unroll
    for (int ks = 0; ks < 4; ++ks)
        a[ks] = *(const bf16x8*)&HNb[(size_t)r * 128 + ks * 32 + quad * 8];
    const f32x4 z = {0.f, 0.f, 0.f, 0.f};
#pragma unroll
    for (int ct = 0; ct < 4; ++ct) {
        f32x4 acc = z;
        const int rb = blockIdx.y * 4 + ct;
#pragma unroll
        for (int ks = 0; ks < 4; ++ks) {
            const bf16x8 bb = *(const bf16x8*)&WF[((rb * 4 + ks) << 9) + tid * 8];
            acc = __builtin_amdgcn_mfma_f32_16x16x32_bf16(bb, a[ks], acc, 0, 0, 0);
        }
        const int col0 = ocol0 + ct * 16 + quad * 4;
        const f32x4 bi4 = ld4bf(&bih[col0]);
        const f32x4 bh4 = ld4bf(&bhh[col0]);
#pragma unroll
        for (int reg = 0; reg < 4; ++reg) acc[reg] += bi4[reg] + bh4[reg];
        const int cta = (ocol0 >> 4) + ct;      // 0..31
        const int w = cta & 7, j = cta >> 3;
        const size_t addr = ((size_t)(blk * 32 + t) * 512 + (w * 64 + quad * 16 + mrow)) * 16 + j * 4;
        *(f32x4*)&GI2[addr] = acc;
    }
}

// ---------------------------------------------------------------------------
// Recurrent LSTM via MFMA. 12 blocks x 512 threads (8 waves), 16 rows/block.
// ---------------------------------------------------------------------------
__global__ __launch_bounds__(512) void k_rec(const float* __restrict__ GI2,
                                             const u16* __restrict__ WhhF,
                                             float* __restrict__ OUTH) {
    __shared__ __align__(16) u16 Abuf[2][16 * 128];
    const int tid = threadIdx.x;
    const int w = tid >> 6, lane = tid & 63;
    const int m = lane & 15, quad = lane >> 4;
    const int blk = blockIdx.x;             // 0..11
    const int q = blk * 16 + m;             // global row b*24+n
    bf16x8 bw[4][4];
#pragma unroll
    for (int j = 0; j < 4; ++j)
#pragma unroll
        for (int ks = 0; ks < 4; ++ks)
            bw[j][ks] = *(const bf16x8*)&WhhF[(((j * 8 + w) * 4 + ks) << 9) + lane * 8];
    const f32x4 z = {0.f, 0.f, 0.f, 0.f};
    f32x4 cst = z;
    bf16x8 a[4];
#pragma unroll
    for (int ks = 0; ks < 4; ++ks) a[ks] = (bf16x8)(short)0;   // h0 = 0
    const float* gb = GI2 + ((size_t)blk * 32 * 512 + tid) * 16;
    f32x4 g[4], gn[4];
#pragma unroll
    for (int j = 0; j < 4; ++j) g[j] = *(const f32x4*)&gb[j * 4];
    const int ws = w * 2 + (quad >> 1);
    const int woff = (quad & 1) * 2;
    for (int t = 0; t < T_; ++t) {
        const int tn = (t + 1 < T_) ? (t + 1) : (T_ - 1);
        const size_t gnb = (size_t)tn * 512 * 16;
#pragma unroll
        for (int j = 0; j < 4; ++j) gn[j] = *(const f32x4*)&gb[gnb + j * 4];
        f32x4 acc[4];
#pragma unroll
        for (int j = 0; j < 4; ++j) acc[j] = z;
#pragma unroll
        for (int j = 0; j < 4; ++j)
#pragma unroll
            for (int ks = 0; ks < 4; ++ks)
                acc[j] = __builtin_amdgcn_mfma_f32_16x16x32_bf16(bw[j][ks], a[ks], acc[j], 0, 0, 0);
        f32x4 hv;
#pragma unroll
        for (int r = 0; r < 4; ++r) {
            const float gi_ = acc[0][r] + g[0][r];
            const float gf_ = acc[1][r] + g[1][r];
            const float gg_ = acc[2][r] + g[2][r];
            const float go_ = acc[3][r] + g[3][r];
            cst[r] = sigm(gf_) * cst[r] + sigm(gi_) * ftanh(gg_);
            hv[r] = sigm(go_) * ftanh(cst[r]);
        }
        *(f32x4*)&OUTH[((size_t)t * 192 + q) * 128 + w * 16 + quad * 4] = hv;
        const u32 lo = (u32)f2bf(hv[0]) | ((u32)f2bf(hv[1]) << 16);
        const u32 hi = (u32)f2bf(hv[2]) | ((u32)f2bf(hv[3]) << 16);
        u32* dst = (u32*)&Abuf[(t + 1) & 1][0];
        *(uint2*)&dst[m * 64 + ((ws ^ m) << 2) + woff] = make_uint2(lo, hi);
        __syncthreads();
        const u16* src = &Abuf[(t + 1) & 1][0];
#pragma unroll
        for (int ks = 0; ks < 4; ++ks)
            a[ks] = *(const bf16x8*)&src[m * 128 + (((ks * 4 + quad) ^ m) << 3)];
#pragma unroll
        for (int j = 0; j < 4; ++j) g[j] = gn[j];
    }
}

// ---------------------------------------------------------------------------
// Readout: out[b,t,n,c] = mask ? OUTH_row . ro_W[c] + ro_b[c] : 0   (fp32 out)
// ---------------------------------------------------------------------------
__global__ __launch_bounds__(256) void k_readout(const float* __restrict__ OUTH,
                                                 const u16* __restrict__ roW,
                                                 const u16* __restrict__ rob,
                                                 const int* __restrict__ nnr,
                                                 float* __restrict__ out) {
    const int idx = blockIdx.x * 256 + threadIdx.x;
    const int btn = idx / C_, c = idx - btn * C_;
    const int bt = btn / N_, n = btn - bt * N_;
    const int b = bt / T_, t = bt - b * T_;
    const int nv = nnr[bt];
    float val = 0.0f;
    if (n < nv) {
        const float* hrow = OUTH + ((size_t)t * 192 + b * N_ + n) * 128;
        const uint2* w2 = (const uint2*)&roW[c * 128];
        float acc = bf2f(rob[c]);
#pragma unroll
        for (int k4 = 0; k4 < 32; ++k4) {
            const float4 h4 = *(const float4*)&hrow[k4 * 4];
            const uint2 ww = w2[k4];
            acc = fmaf(bf2f((u16)ww.x), h4.x,
                  fmaf(bf2f((u16)(ww.x >> 16)), h4.y,
                  fmaf(bf2f((u16)ww.y), h4.z,
                  fmaf(bf2f((u16)(ww.y >> 16)), h4.w, acc))));
        }
        val = acc;
    }
    out[idx] = val;
}

// ---------------------------------------------------------------------------
extern "C" void kernel_launch(void* const* d_in, const int* in_sizes, int n_in,
                              void* d_out, int out_size, void* d_ws, size_t ws_size,
                              hipStream_t stream) {
    const float* node = (const float*)d_in[0];
    const float* edge = (const float*)d_in[1];
    const int* nnr = (const int*)d_in[19];

    // Workspace layout (~62 MB)
    char* ws = (char*)d_ws;
    float* HN = (float*)ws;   ws += (size_t)BTN_ * D_ * 4;    // 3.15 MB
    u16* HNb = (u16*)ws;      ws += (size_t)BTN_ * D_ * 2;    // 1.57 MB
    float* XW = (float*)ws;   ws += (size_t)BTN_ * D_ * 4;    // 3.15 MB (OUTH only now)
    u16* MVb = (u16*)ws;      ws += (size_t)BTN_ * D_ * 2;    // 1.57 MB
    float* ADJ = (float*)ws;  ws += (size_t)BTVW_ * 4;        // 0.59 MB
    float* GI = (float*)ws;   ws += (size_t)BTN_ * 512 * 4;   // 12.58 MB (GI2 layout)
    u16* WThh = (u16*)ws;     ws += 65536 * 2;                // 0.13 MB (unused, kept)
    u16* ME = (u16*)ws;       ws += (size_t)BTVW_ * D_ * 2;   // 37.75 MB
    float* OUTH = XW;

    // Weight slots (same 17-slot layout; the 7 big ones hold FRAGMENT-LINEAR
    // bf16; the 10 small ones canonical bf16) — all written by k_preproc.
    u16* cbase = (u16*)ws;
    const int cvtN17[17] = {16384, 128, 128, 1, 16384, 16384, 128,
                            49152, 49152, 384, 384, 65536, 65536, 512, 512, 768, 6};
    u16* cptr[17];
    {
        int off = 0;
        for (int i = 0; i < 17; ++i) {
            cptr[i] = cbase + off;
            off += (cvtN17[i] + 7) & ~7;
        }
    }
    PreArgs pa;
    pa.node = node; pa.HN = HN; pa.HNb = HNb;
    {
        const int din_idx[7] = {2, 6, 7, 9, 10, 13, 14};
        const int slot[7]    = {0, 4, 5, 7,  8, 11, 12};
        const int nelem[7]   = {16384, 16384, 16384, 49152, 49152, 65536, 65536};
        int cum = 0;
        for (int i = 0; i < 7; ++i) {
            pa.fsrc[i] = (const float*)d_in[din_idx[i]];
            pa.fdst[i] = cptr[slot[i]];
            pa.fstart[i] = cum;
            cum += nelem[i];
        }
        pa.fstart[7] = cum;             // 278528 = 1088 * 256
    }
    {
        const int din_idx[10] = {3, 4, 5, 8, 11, 12, 15, 16, 17, 18};
        const int slot[10]    = {1, 2, 3, 6,  9, 10, 13, 14, 15, 16};
        const int nelem[10]   = {128, 128, 1, 128, 384, 384, 512, 512, 768, 6};
        int cum = 0;
        for (int i = 0; i < 10; ++i) {
            pa.csrc[i] = d_in[din_idx[i]];
            pa.cdst[i] = cptr[slot[i]];
            pa.cstart[i] = cum;
            cum += nelem[i];
        }
        pa.cstart[10] = cum;            // 2951
    }
    u16* fW1 = cptr[0];  u16* cb1 = cptr[1];  u16* cW2 = cptr[2];  u16* cb2 = cptr[3];
    u16* fWh = cptr[4];  u16* fWe = cptr[5];  u16* cmb = cptr[6];
    u16* fgWih = cptr[7]; u16* fgWhh = cptr[8]; u16* cgbih = cptr[9]; u16* cgbhh = cptr[10];
    u16* flsWih = cptr[11]; u16* flsWhh = cptr[12]; u16* clsbih = cptr[13]; u16* clsbhh = cptr[14];
    u16* croW = cptr[15]; u16* crob = cptr[16];
    (void)WThh;

    k_preproc<<<1356, 256, 0, stream>>>(pa);
    k_prep<<<BT_ * 18, 128, 0, stream>>>(edge, fWe, fW1, cb1, cW2, cb2, ME, ADJ);
    for (int l = 0; l < P_; ++l) {
        if (l < P_ - 1)
            k_fused<true><<<BTN_ / 2, 256, 0, stream>>>(ME, HNb, fWh, cmb, fW1, cb1, cW2, cb2,
                                                        nnr, ADJ, MVb);
        else
            k_fused<false><<<BTN_ / 2, 256, 0, stream>>>(ME, HNb, fWh, cmb, fW1, cb1, cW2, cb2,
                                                         nnr, ADJ, MVb);
        k_gruM<<<dim3(384, 4), 64, 0, stream>>>(MVb, HNb, HN, HNb, fgWih, fgWhh, cgbih, cgbhh, nnr);
    }
    k_gi<<<dim3(384, 8), 64, 0, stream>>>(HNb, flsWih, clsbih, clsbhh, GI);
    k_rec<<<12, 512, 0, stream>>>(GI, flsWhh, OUTH);
    k_readout<<<144, 256, 0, stream>>>(OUTH, croW, crob, nnr, (float*)d_out);
}

// Round 12
// 314.219 us; speedup vs baseline: 1.0335x; 1.0335x over previous
//
#include <hip/hip_runtime.h>
#include <cmath>

typedef unsigned short u16;
typedef unsigned int   u32;
typedef short bf16x8 __attribute__((ext_vector_type(8)));
typedef float f32x4 __attribute__((ext_vector_type(4)));

// Problem constants
constexpr int B_ = 8, T_ = 32, N_ = 24, D_ = 128;
constexpr int BT_ = B_ * T_;            // 256
constexpr int VW_ = N_ * N_;            // 576
constexpr int BTN_ = BT_ * N_;          // 6144
constexpr int BTVW_ = BT_ * VW_;        // 147456
constexpr int P_ = 3;
constexpr int C_ = 6;
constexpr int SA_ = 136;                // k_fused A row stride (u16); /2=68 u32

__device__ __forceinline__ float bits2f(u32 u) { float f; __builtin_memcpy(&f, &u, 4); return f; }
__device__ __forceinline__ float bf2f(u16 h) { return bits2f(((u32)h) << 16); }
__device__ __forceinline__ u16 f2bf(float f) {
    u32 u; __builtin_memcpy(&u, &f, 4);
    u32 r = u + 0x7FFFu + ((u >> 16) & 1u);
    return (u16)(r >> 16);
}
__device__ __forceinline__ f32x4 ld4bf(const u16* p) {
    const uint2 v = *(const uint2*)p;
    f32x4 r;
    r[0] = bf2f((u16)v.x); r[1] = bf2f((u16)(v.x >> 16));
    r[2] = bf2f((u16)v.y); r[3] = bf2f((u16)(v.y >> 16));
    return r;
}
// Fast activations via hardware v_exp_f32 / v_rcp_f32 (error ~1e-6).
__device__ __forceinline__ float fexp2(float x) { return __builtin_amdgcn_exp2f(x); }
__device__ __forceinline__ float frcp(float x) { return __builtin_amdgcn_rcpf(x); }
__device__ __forceinline__ float sigm(float x) {
    return frcp(1.0f + fexp2(x * -1.4426950408889634f));
}
__device__ __forceinline__ float ftanh(float x) {
    const float t = fexp2(fabsf(x) * -2.8853900817779268f);
    return copysignf((1.0f - t) * frcp(1.0f + t), x);
}

// ---------------------------------------------------------------------------
// Merged preprocessing: node transpose (blocks 0..255) + fragment-linear
// weight repack (blocks 256..1343) + small-array bf16 convert (1344..1355).
// ---------------------------------------------------------------------------
struct PreArgs {
    const float* node; float* HN; u16* HNb;
    const float* fsrc[7]; u16* fdst[7]; int fstart[8];
    const void* csrc[10]; u16* cdst[10]; int cstart[11];
};

__global__ __launch_bounds__(256) void k_preproc(PreArgs a) {
    const int bx = blockIdx.x;
    if (bx < 256) {
        const int bt = bx;
        for (int f = threadIdx.x; f < 3072; f += 256) {
            const int d = f / 24, n = f - d * 24;
            const float v = a.node[(size_t)bt * 3072 + f];
            a.HN[(size_t)bt * 3072 + n * 128 + d] = v;
            a.HNb[(size_t)bt * 3072 + n * 128 + d] = f2bf(v);
        }
    } else if (bx < 1344) {
        // FL[((rb*4+ks)*64 + lane)*8 + e] = W[(rb*16+m)*128 + ks*32 + quad*8 + e]
        const int idx = (bx - 256) * 256 + threadIdx.x;
        if (idx >= a.fstart[7]) return;
        int s = 0;
#pragma unroll
        for (int i = 1; i < 7; ++i) s += (idx >= a.fstart[i]) ? 1 : 0;
        const int off = idx - a.fstart[s];
        const int e = off & 7, lane = (off >> 3) & 63;
        const int ks = (off >> 9) & 3, rb = off >> 11;
        const int m = lane & 15, quad = lane >> 4;
        a.fdst[s][off] = f2bf(a.fsrc[s][(size_t)(rb * 16 + m) * 128 + ks * 32 + quad * 8 + e]);
    } else {
        const int idx = (bx - 1344) * 256 + threadIdx.x;
        if (idx >= a.cstart[10]) return;
        int s = 0;
#pragma unroll
        for (int i = 1; i < 10; ++i) s += (idx >= a.cstart[i]) ? 1 : 0;
        const int off = idx - a.cstart[s];
        a.cdst[s][off] = f2bf(((const float*)a.csrc[s])[off]);
    }
}

// ---------------------------------------------------------------------------
// k_prep: fused edge transpose + ME GEMM + layer-0 link-MLP.
// TWO waves per 32-row tile (R11, measured 45.5us < 47 one-wave): both
// waves stage cooperatively, then wave0 runs the ME pass and wave1 the
// link pass in parallel — halves the per-wave serial load->MFMA chain.
// ---------------------------------------------------------------------------
__global__ __launch_bounds__(128) void k_prep(
    const float* __restrict__ edge, const u16* __restrict__ WeF,
    const u16* __restrict__ W1F, const u16* __restrict__ b1,
    const u16* __restrict__ W2, const u16* __restrict__ b2,
    u16* __restrict__ ME, float* __restrict__ ADJ) {
    __shared__ __align__(16) u16 A[32 * 128];   // swizzled, 8 KB
    const int tid = threadIdx.x;                // 0..127
    const int bt = blockIdx.x / 18, tile = blockIdx.x % 18;
    const int vw0 = tile * 32;
    const size_t ebase = (size_t)bt * D_ * VW_ + vw0;
    // ---- staging: 8 float4 loads/lane across 128 threads ----
    const int vq = tid & 7, dg = tid >> 3;      // vq: vw-quad (8), dg: d-pair group (16)
    u32* A32 = (u32*)A;
    {
        float4 fa[4], fb[4];
#pragma unroll
        for (int it = 0; it < 4; ++it) {
            const int d0 = it * 32 + dg * 2;
            fa[it] = *(const float4*)&edge[ebase + (size_t)d0 * VW_ + vq * 4];
            fb[it] = *(const float4*)&edge[ebase + (size_t)(d0 + 1) * VW_ + vq * 4];
        }
#pragma unroll
        for (int it = 0; it < 4; ++it) {
            const int d0 = it * 32 + dg * 2;
            const float* pa = (const float*)&fa[it];
            const float* pb = (const float*)&fb[it];
#pragma unroll
            for (int i = 0; i < 4; ++i) {
                const int row = vq * 4 + i;
                const int sw32 = ((row >> 2) & 7) * 4;
                A32[row * 64 + ((d0 >> 1) ^ sw32)] =
                    (u32)f2bf(pa[i]) | ((u32)f2bf(pb[i]) << 16);
            }
        }
    }
    __syncthreads();
    const int wv = tid >> 6, lane = tid & 63;
    const int m = lane & 15, quad = lane >> 4;
    bf16x8 a[2][4];
#pragma unroll
    for (int rt = 0; rt < 2; ++rt) {
        const int row = rt * 16 + m;
        const int sw16 = ((row >> 2) & 7) * 8;
#pragma unroll
        for (int ks = 0; ks < 4; ++ks)
            a[rt][ks] = *(const bf16x8*)&A[row * 128 + ((ks * 32 + quad * 8) ^ sw16)];
    }
    const f32x4 z = {0.f, 0.f, 0.f, 0.f};
    if (wv == 0) {
        // ---- ME = A @ We^T (swapped operands -> coalesced uint2 stores) ----
#pragma unroll
        for (int ct = 0; ct < 8; ++ct) {
            bf16x8 bw[4];
#pragma unroll
            for (int ks = 0; ks < 4; ++ks)
                bw[ks] = *(const bf16x8*)&WeF[((ct * 4 + ks) << 9) + lane * 8];
            f32x4 acc[2];
#pragma unroll
            for (int rt = 0; rt < 2; ++rt) acc[rt] = z;
#pragma unroll
            for (int rt = 0; rt < 2; ++rt)
#pragma unroll
                for (int ks = 0; ks < 4; ++ks)
                    acc[rt] = __builtin_amdgcn_mfma_f32_16x16x32_bf16(bw[ks], a[rt][ks], acc[rt], 0, 0, 0);
#pragma unroll
            for (int rt = 0; rt < 2; ++rt) {
                const u32 lo = (u32)f2bf(acc[rt][0]) | ((u32)f2bf(acc[rt][1]) << 16);
                const u32 hi = (u32)f2bf(acc[rt][2]) | ((u32)f2bf(acc[rt][3]) << 16);
                *(uint2*)&ME[(size_t)(bt * VW_ + vw0 + rt * 16 + m) * 128 + ct * 16 + quad * 4] =
                    make_uint2(lo, hi);
            }
        }
    } else {
        // ---- layer-0 adjacency: relu(W1@A + b1) . W2 + b2 ----
        float p[2][4] = {};
        const float b2v = bf2f(b2[0]);
#pragma unroll
        for (int ct = 0; ct < 8; ++ct) {
            bf16x8 bw[4];
#pragma unroll
            for (int ks = 0; ks < 4; ++ks)
                bw[ks] = *(const bf16x8*)&W1F[((ct * 4 + ks) << 9) + lane * 8];
            f32x4 acc[2];
#pragma unroll
            for (int rt = 0; rt < 2; ++rt) acc[rt] = z;
#pragma unroll
            for (int rt = 0; rt < 2; ++rt)
#pragma unroll
                for (int ks = 0; ks < 4; ++ks)
                    acc[rt] = __builtin_amdgcn_mfma_f32_16x16x32_bf16(a[rt][ks], bw[ks], acc[rt], 0, 0, 0);
            const int n = ct * 16 + m;
            const float b1v = bf2f(b1[n]);
            const float w2v = bf2f(W2[n]);
#pragma unroll
            for (int rt = 0; rt < 2; ++rt)
#pragma unroll
                for (int reg = 0; reg < 4; ++reg)
                    p[rt][reg] += fmaxf(acc[rt][reg] + b1v, 0.0f) * w2v;
        }
#pragma unroll
        for (int rt = 0; rt < 2; ++rt)
#pragma unroll
            for (int reg = 0; reg < 4; ++reg) {
                float v = p[rt][reg];
                v += __shfl_xor(v, 1);
                v += __shfl_xor(v, 2);
                v += __shfl_xor(v, 4);
                v += __shfl_xor(v, 8);
                p[rt][reg] = v;
            }
        if (m == 0) {
#pragma unroll
            for (int rt = 0; rt < 2; ++rt)
#pragma unroll
                for (int reg = 0; reg < 4; ++reg)
                    ADJ[bt * VW_ + vw0 + rt * 16 + quad * 4 + reg] = p[rt][reg] + b2v;
        }
    }
}

// ---------------------------------------------------------------------------
// Fused per-(bt, v-pair) edge kernel (R10 form: XW from global — the
// in-block XW recompute was 12x-redundant and regressed, R11 post-mortem).
// ---------------------------------------------------------------------------
template <bool ADJP>
__global__ __launch_bounds__(256) void k_fused(
    const u16* __restrict__ ME, const float* __restrict__ XW,
    const u16* __restrict__ mb,
    const u16* __restrict__ W1F, const u16* __restrict__ b1,
    const u16* __restrict__ W2, const u16* __restrict__ b2,
    const int* __restrict__ nnr, float* __restrict__ ADJ,
    u16* __restrict__ MVb) {
    __shared__ __align__(16) u16 A[48 * SA_];
    __shared__ float gate_s[48];
    __shared__ float2 mvp[2][2][64];
    const int tid = threadIdx.x;
    const int blk = blockIdx.x;
    const int bt = blk / 12, pr = blk - bt * 12;
    const int v0 = pr * 2;
    const int e0 = bt * VW_ + v0 * N_;
    const int nv = nnr[bt];

    if (tid < 48) gate_s[tid] = sigm(ADJ[e0 + tid]);
    __syncthreads();
    {
        const int op = tid & 63;
        const int sub = (tid >> 6) & 1;
        const int grp = tid >> 7;
        const int v = v0 + grp;
        const u32 mbu = ((const u32*)mb)[op];
        const float mb0 = bf2f((u16)mbu), mb1 = bf2f((u16)(mbu >> 16));
        const bool vva = v < nv;
        u32 meR[12]; float2 xwR[12];
#pragma unroll
        for (int i = 0; i < 12; ++i) {
            const int w = sub * 12 + i;
            const int rr = grp * 24 + w;
            meR[i] = ((const u32*)ME)[(size_t)(e0 + rr) * 64 + op];
            xwR[i] = *(const float2*)&XW[(size_t)(bt * N_ + w) * 128 + 2 * op];
        }
        float mvx = 0.0f, mvy = 0.0f;
        u32* A32 = (u32*)A;
#pragma unroll
        for (int i = 0; i < 12; ++i) {
            const int w = sub * 12 + i;
            const int rr = grp * 24 + w;
            float v0f = 0.0f, v1f = 0.0f;
            if (vva && w < nv) {
                const float g = gate_s[rr];
                v0f = g * fmaxf(xwR[i].x + bf2f((u16)meR[i]) + mb0, 0.0f);
                v1f = g * fmaxf(xwR[i].y + bf2f((u16)(meR[i] >> 16)) + mb1, 0.0f);
                mvx += v0f; mvy += v1f;
            }
            if (ADJP) A32[rr * 68 + op] = (u32)f2bf(v0f) | ((u32)f2bf(v1f) << 16);
        }
        mvp[grp][sub][op] = make_float2(mvx, mvy);
    }
    __syncthreads();
    if (tid < 128) {
        const int g2 = tid >> 6, o2 = tid & 63;
        const float2 pa = mvp[g2][0][o2], pb = mvp[g2][1][o2];
        ((u32*)MVb)[(size_t)(bt * N_ + v0 + g2) * 64 + o2] =
            (u32)f2bf(pa.x + pb.x) | ((u32)f2bf(pa.y + pb.y) << 16);
    }

    if constexpr (ADJP) {
        __syncthreads();
        if (tid >= 64) return;
        const int m = tid & 15, quad = tid >> 4;
        bf16x8 a[3][4];
#pragma unroll
        for (int rt = 0; rt < 3; ++rt)
#pragma unroll
            for (int ks = 0; ks < 4; ++ks)
                a[rt][ks] = *(const bf16x8*)&A[(rt * 16 + m) * SA_ + ks * 32 + quad * 8];
        const f32x4 z = {0.f, 0.f, 0.f, 0.f};
        float p[3][4] = {};
        const float b2v = bf2f(b2[0]);
#pragma unroll
        for (int ct = 0; ct < 8; ++ct) {
            bf16x8 bw[4];
#pragma unroll
            for (int ks = 0; ks < 4; ++ks)
                bw[ks] = *(const bf16x8*)&W1F[((ct * 4 + ks) << 9) + tid * 8];
            f32x4 acc[3];
#pragma unroll
            for (int rt = 0; rt < 3; ++rt) acc[rt] = z;
#pragma unroll
            for (int rt = 0; rt < 3; ++rt)
#pragma unroll
                for (int ks = 0; ks < 4; ++ks)
                    acc[rt] = __builtin_amdgcn_mfma_f32_16x16x32_bf16(a[rt][ks], bw[ks], acc[rt], 0, 0, 0);
            const int n = ct * 16 + m;
            const float b1v = bf2f(b1[n]);
            const float w2v = bf2f(W2[n]);
#pragma unroll
            for (int rt = 0; rt < 3; ++rt)
#pragma unroll
                for (int reg = 0; reg < 4; ++reg)
                    p[rt][reg] += fmaxf(acc[rt][reg] + b1v, 0.0f) * w2v;
        }
#pragma unroll
        for (int rt = 0; rt < 3; ++rt)
#pragma unroll
            for (int reg = 0; reg < 4; ++reg) {
                float v = p[rt][reg];
                v += __shfl_xor(v, 1);
                v += __shfl_xor(v, 2);
                v += __shfl_xor(v, 4);
                v += __shfl_xor(v, 8);
                p[rt][reg] = v;
            }
        if (m == 0) {
#pragma unroll
            for (int rt = 0; rt < 3; ++rt)
#pragma unroll
                for (int reg = 0; reg < 4; ++reg)
                    ADJ[e0 + rt * 16 + quad * 4 + reg] = p[rt][reg] + b2v;
        }
    }
}

// ---------------------------------------------------------------------------
// XW = HNb @ msg_Wh^T. grid (384,4) x 64: 1 wave = 16 rows x 2 col-tiles.
// ---------------------------------------------------------------------------
__global__ __launch_bounds__(64, 1) void k_xw(const u16* __restrict__ HNb,
                                              const u16* __restrict__ WhF,
                                              float* __restrict__ XW) {
    const int tid = threadIdx.x;
    const int m = tid & 15, quad = tid >> 4;
    const int r0 = blockIdx.x * 16;
    const int ct0 = blockIdx.y * 2;
    bf16x8 a[4];
#pragma unroll
    for (int ks = 0; ks < 4; ++ks)
        a[ks] = *(const bf16x8*)&HNb[(size_t)(r0 + m) * 128 + ks * 32 + quad * 8];
    const f32x4 z = {0.f, 0.f, 0.f, 0.f};
#pragma unroll
    for (int cti = 0; cti < 2; ++cti) {
        const int ct = ct0 + cti;
        f32x4 acc = z;
#pragma unroll
        for (int ks = 0; ks < 4; ++ks) {
            const bf16x8 b = *(const bf16x8*)&WhF[((ct * 4 + ks) << 9) + tid * 8];
            acc = __builtin_amdgcn_mfma_f32_16x16x32_bf16(b, a[ks], acc, 0, 0, 0);
        }
        *(f32x4*)&XW[(size_t)(r0 + m) * 128 + ct * 16 + quad * 4] = acc;
    }
}

// ---------------------------------------------------------------------------
// Fused MFMA GRU. grid (384,4) x 64: 1 wave = 16 rows x 2 col-tiles.
// ---------------------------------------------------------------------------
__global__ __launch_bounds__(64, 1) void k_gruM(
    const u16* __restrict__ MVb, const u16* __restrict__ HNb_in,
    float* __restrict__ HN, u16* __restrict__ HNb,
    const u16* __restrict__ WihF, const u16* __restrict__ WhhF,
    const u16* __restrict__ bih, const u16* __restrict__ bhh,
    const int* __restrict__ nnr) {
    const int tid = threadIdx.x;
    const int m = tid & 15, quad = tid >> 4;
    const int rbase = blockIdx.x * 16;
    const int ct0 = blockIdx.y * 2;
    bf16x8 amv[4], ahn[4];
#pragma unroll
    for (int ks = 0; ks < 4; ++ks) {
        amv[ks] = *(const bf16x8*)&MVb[(size_t)(rbase + m) * 128 + ks * 32 + quad * 8];
        ahn[ks] = *(const bf16x8*)&HNb_in[(size_t)(rbase + m) * 128 + ks * 32 + quad * 8];
    }
    const int myrow = rbase + m;
    const int mybt = myrow / N_;
    const bool valid = (myrow - mybt * N_) < nnr[mybt];
    const f32x4 z = {0.f, 0.f, 0.f, 0.f};
#pragma unroll
    for (int cti = 0; cti < 2; ++cti) {
        const int ct = ct0 + cti;
        f32x4 gi[3], gh[3];
#pragma unroll
        for (int g = 0; g < 3; ++g) { gi[g] = z; gh[g] = z; }
#pragma unroll
        for (int g = 0; g < 3; ++g) {
            const int rb = g * 8 + ct;
#pragma unroll
            for (int ks = 0; ks < 4; ++ks) {
                const bf16x8 bi_f = *(const bf16x8*)&WihF[((rb * 4 + ks) << 9) + tid * 8];
                const bf16x8 bh_f = *(const bf16x8*)&WhhF[((rb * 4 + ks) << 9) + tid * 8];
                gi[g] = __builtin_amdgcn_mfma_f32_16x16x32_bf16(bi_f, amv[ks], gi[g], 0, 0, 0);
                gh[g] = __builtin_amdgcn_mfma_f32_16x16x32_bf16(bh_f, ahn[ks], gh[g], 0, 0, 0);
            }
        }
        const int col0 = ct * 16 + quad * 4;
        const f32x4 biR = ld4bf(&bih[col0]),       bhR = ld4bf(&bhh[col0]);
        const f32x4 biZ = ld4bf(&bih[128 + col0]), bhZ = ld4bf(&bhh[128 + col0]);
        const f32x4 biN = ld4bf(&bih[256 + col0]), bhN = ld4bf(&bhh[256 + col0]);
        const size_t oi = (size_t)myrow * 128 + col0;
        const f32x4 hold = *(const f32x4*)&HN[oi];
        f32x4 hv;
#pragma unroll
        for (int reg = 0; reg < 4; ++reg) {
            const float r  = sigm(gi[0][reg] + gh[0][reg] + biR[reg] + bhR[reg]);
            const float zz = sigm(gi[1][reg] + gh[1][reg] + biZ[reg] + bhZ[reg]);
            const float nn = ftanh(gi[2][reg] + biN[reg] + r * (gh[2][reg] + bhN[reg]));
            hv[reg] = valid ? ((1.0f - zz) * nn + zz * hold[reg]) : 0.0f;
        }
        *(f32x4*)&HN[oi] = hv;
        const u32 lo = (u32)f2bf(hv[0]) | ((u32)f2bf(hv[1]) << 16);
        const u32 hi = (u32)f2bf(hv[2]) | ((u32)f2bf(hv[3]) << 16);
        *(uint2*)&HNb[oi] = make_uint2(lo, hi);
    }
}

// ---------------------------------------------------------------------------
// GI2 = HNb @ lstm_Wih^T + (bih+bhh) in k_rec's MFMA-lane layout.
// grid (384,8) x 64: 1 wave = 16 rows x 4 col-tiles.
// ---------------------------------------------------------------------------
__global__ __launch_bounds__(64, 2) void k_gi(const u16* __restrict__ HNb,
                                              const u16* __restrict__ WF,
                                              const u16* __restrict__ bih, const u16* __restrict__ bhh,
                                              float* __restrict__ GI2) {
    const int tid = threadIdx.x;
    const int m = tid & 15, quad = tid >> 4;
    const int r0 = blockIdx.x * 16;
    const int ocol0 = blockIdx.y * 64;
    const int r = r0 + m;
    const int btq = r / 24, n = r - btq * 24;
    const int b = btq >> 5, t = btq & 31;
    const int q = b * 24 + n;
    const int blk = q >> 4, mrow = q & 15;
    bf16x8 a[4];
#pragma unroll
    for (int ks = 0; ks < 4; ++ks)
        a[ks] = *(const bf16x8*)&HNb[(size_t)r * 128 + ks * 32 + quad * 8];
    const f32x4 z = {0.f, 0.f, 0.f, 0.f};
#pragma unroll
    for (int ct = 0; ct < 4; ++ct) {
        f32x4 acc = z;
        const int rb = blockIdx.y * 4 + ct;
#pragma unroll
        for (int ks = 0; ks < 4; ++ks) {
            const bf16x8 bb = *(const bf16x8*)&WF[((rb * 4 + ks) << 9) + tid * 8];
            acc = __builtin_amdgcn_mfma_f32_16x16x32_bf16(bb, a[ks], acc, 0, 0, 0);
        }
        const int col0 = ocol0 + ct * 16 + quad * 4;
        const f32x4 bi4 = ld4bf(&bih[col0]);
        const f32x4 bh4 = ld4bf(&bhh[col0]);
#pragma unroll
        for (int reg = 0; reg < 4; ++reg) acc[reg] += bi4[reg] + bh4[reg];
        const int cta = (ocol0 >> 4) + ct;      // 0..31
        const int w = cta & 7, j = cta >> 3;
        const size_t addr = ((size_t)(blk * 32 + t) * 512 + (w * 64 + quad * 16 + mrow)) * 16 + j * 4;
        *(f32x4*)&GI2[addr] = acc;
    }
}

// ---------------------------------------------------------------------------
// Recurrent LSTM via MFMA. 12 blocks x 512 threads (8 waves), 16 rows/block.
// ---------------------------------------------------------------------------
__global__ __launch_bounds__(512) void k_rec(const float* __restrict__ GI2,
                                             const u16* __restrict__ WhhF,
                                             float* __restrict__ OUTH) {
    __shared__ __align__(16) u16 Abuf[2][16 * 128];
    const int tid = threadIdx.x;
    const int w = tid >> 6, lane = tid & 63;
    const int m = lane & 15, quad = lane >> 4;
    const int blk = blockIdx.x;             // 0..11
    const int q = blk * 16 + m;             // global row b*24+n
    bf16x8 bw[4][4];
#pragma unroll
    for (int j = 0; j < 4; ++j)
#pragma unroll
        for (int ks = 0; ks < 4; ++ks)
            bw[j][ks] = *(const bf16x8*)&WhhF[(((j * 8 + w) * 4 + ks) << 9) + lane * 8];
    const f32x4 z = {0.f, 0.f, 0.f, 0.f};
    f32x4 cst = z;
    bf16x8 a[4];
#pragma unroll
    for (int ks = 0; ks < 4; ++ks) a[ks] = (bf16x8)(short)0;   // h0 = 0
    const float* gb = GI2 + ((size_t)blk * 32 * 512 + tid) * 16;
    f32x4 g[4], gn[4];
#pragma unroll
    for (int j = 0; j < 4; ++j) g[j] = *(const f32x4*)&gb[j * 4];
    const int ws = w * 2 + (quad >> 1);
    const int woff = (quad & 1) * 2;
    for (int t = 0; t < T_; ++t) {
        const int tn = (t + 1 < T_) ? (t + 1) : (T_ - 1);
        const size_t gnb = (size_t)tn * 512 * 16;
#pragma unroll
        for (int j = 0; j < 4; ++j) gn[j] = *(const f32x4*)&gb[gnb + j * 4];
        f32x4 acc[4];
#pragma unroll
        for (int j = 0; j < 4; ++j) acc[j] = z;
#pragma unroll
        for (int j = 0; j < 4; ++j)
#pragma unroll
            for (int ks = 0; ks < 4; ++ks)
                acc[j] = __builtin_amdgcn_mfma_f32_16x16x32_bf16(bw[j][ks], a[ks], acc[j], 0, 0, 0);
        f32x4 hv;
#pragma unroll
        for (int r = 0; r < 4; ++r) {
            const float gi_ = acc[0][r] + g[0][r];
            const float gf_ = acc[1][r] + g[1][r];
            const float gg_ = acc[2][r] + g[2][r];
            const float go_ = acc[3][r] + g[3][r];
            cst[r] = sigm(gf_) * cst[r] + sigm(gi_) * ftanh(gg_);
            hv[r] = sigm(go_) * ftanh(cst[r]);
        }
        *(f32x4*)&OUTH[((size_t)t * 192 + q) * 128 + w * 16 + quad * 4] = hv;
        const u32 lo = (u32)f2bf(hv[0]) | ((u32)f2bf(hv[1]) << 16);
        const u32 hi = (u32)f2bf(hv[2]) | ((u32)f2bf(hv[3]) << 16);
        u32* dst = (u32*)&Abuf[(t + 1) & 1][0];
        *(uint2*)&dst[m * 64 + ((ws ^ m) << 2) + woff] = make_uint2(lo, hi);
        __syncthreads();
        const u16* src = &Abuf[(t + 1) & 1][0];
#pragma unroll
        for (int ks = 0; ks < 4; ++ks)
            a[ks] = *(const bf16x8*)&src[m * 128 + (((ks * 4 + quad) ^ m) << 3)];
#pragma unroll
        for (int j = 0; j < 4; ++j) g[j] = gn[j];
    }
}

// ---------------------------------------------------------------------------
// Readout: out[b,t,n,c] = mask ? OUTH_row . ro_W[c] + ro_b[c] : 0   (fp32 out)
// ---------------------------------------------------------------------------
__global__ __launch_bounds__(256) void k_readout(const float* __restrict__ OUTH,
                                                 const u16* __restrict__ roW,
                                                 const u16* __restrict__ rob,
                                                 const int* __restrict__ nnr,
                                                 float* __restrict__ out) {
    const int idx = blockIdx.x * 256 + threadIdx.x;
    const int btn = idx / C_, c = idx - btn * C_;
    const int bt = btn / N_, n = btn - bt * N_;
    const int b = bt / T_, t = bt - b * T_;
    const int nv = nnr[bt];
    float val = 0.0f;
    if (n < nv) {
        const float* hrow = OUTH + ((size_t)t * 192 + b * N_ + n) * 128;
        const uint2* w2 = (const uint2*)&roW[c * 128];
        float acc = bf2f(rob[c]);
#pragma unroll
        for (int k4 = 0; k4 < 32; ++k4) {
            const float4 h4 = *(const float4*)&hrow[k4 * 4];
            const uint2 ww = w2[k4];
            acc = fmaf(bf2f((u16)ww.x), h4.x,
                  fmaf(bf2f((u16)(ww.x >> 16)), h4.y,
                  fmaf(bf2f((u16)ww.y), h4.z,
                  fmaf(bf2f((u16)(ww.y >> 16)), h4.w, acc))));
        }
        val = acc;
    }
    out[idx] = val;
}

// ---------------------------------------------------------------------------
extern "C" void kernel_launch(void* const* d_in, const int* in_sizes, int n_in,
                              void* d_out, int out_size, void* d_ws, size_t ws_size,
                              hipStream_t stream) {
    const float* node = (const float*)d_in[0];
    const float* edge = (const float*)d_in[1];
    const int* nnr = (const int*)d_in[19];

    // Workspace layout (~62 MB)
    char* ws = (char*)d_ws;
    float* HN = (float*)ws;   ws += (size_t)BTN_ * D_ * 4;    // 3.15 MB
    u16* HNb = (u16*)ws;      ws += (size_t)BTN_ * D_ * 2;    // 1.57 MB
    float* XW = (float*)ws;   ws += (size_t)BTN_ * D_ * 4;    // 3.15 MB
    u16* MVb = (u16*)ws;      ws += (size_t)BTN_ * D_ * 2;    // 1.57 MB
    float* ADJ = (float*)ws;  ws += (size_t)BTVW_ * 4;        // 0.59 MB
    float* GI = (float*)ws;   ws += (size_t)BTN_ * 512 * 4;   // 12.58 MB (GI2 layout)
    u16* WThh = (u16*)ws;     ws += 65536 * 2;                // 0.13 MB (unused, kept)
    u16* ME = (u16*)ws;       ws += (size_t)BTVW_ * D_ * 2;   // 37.75 MB
    float* OUTH = XW;         // XW dead after last k_fused; same size

    // Weight slots (same 17-slot layout; the 7 big ones hold FRAGMENT-LINEAR
    // bf16; the 10 small ones canonical bf16) — all written by k_preproc.
    u16* cbase = (u16*)ws;
    const int cvtN17[17] = {16384, 128, 128, 1, 16384, 16384, 128,
                            49152, 49152, 384, 384, 65536, 65536, 512, 512, 768, 6};
    u16* cptr[17];
    {
        int off = 0;
        for (int i = 0; i < 17; ++i) {
            cptr[i] = cbase + off;
            off += (cvtN17[i] + 7) & ~7;
        }
    }
    PreArgs pa;
    pa.node = node; pa.HN = HN; pa.HNb = HNb;
    {
        const int din_idx[7] = {2, 6, 7, 9, 10, 13, 14};
        const int slot[7]    = {0, 4, 5, 7,  8, 11, 12};
        const int nelem[7]   = {16384, 16384, 16384, 49152, 49152, 65536, 65536};
        int cum = 0;
        for (int i = 0; i < 7; ++i) {
            pa.fsrc[i] = (const float*)d_in[din_idx[i]];
            pa.fdst[i] = cptr[slot[i]];
            pa.fstart[i] = cum;
            cum += nelem[i];
        }
        pa.fstart[7] = cum;             // 278528 = 1088 * 256
    }
    {
        const int din_idx[10] = {3, 4, 5, 8, 11, 12, 15, 16, 17, 18};
        const int slot[10]    = {1, 2, 3, 6,  9, 10, 13, 14, 15, 16};
        const int nelem[10]   = {128, 128, 1, 128, 384, 384, 512, 512, 768, 6};
        int cum = 0;
        for (int i = 0; i < 10; ++i) {
            pa.csrc[i] = d_in[din_idx[i]];
            pa.cdst[i] = cptr[slot[i]];
            pa.cstart[i] = cum;
            cum += nelem[i];
        }
        pa.cstart[10] = cum;            // 2951
    }
    u16* fW1 = cptr[0];  u16* cb1 = cptr[1];  u16* cW2 = cptr[2];  u16* cb2 = cptr[3];
    u16* fWh = cptr[4];  u16* fWe = cptr[5];  u16* cmb = cptr[6];
    u16* fgWih = cptr[7]; u16* fgWhh = cptr[8]; u16* cgbih = cptr[9]; u16* cgbhh = cptr[10];
    u16* flsWih = cptr[11]; u16* flsWhh = cptr[12]; u16* clsbih = cptr[13]; u16* clsbhh = cptr[14];
    u16* croW = cptr[15]; u16* crob = cptr[16];
    (void)WThh;

    k_preproc<<<1356, 256, 0, stream>>>(pa);
    k_prep<<<BT_ * 18, 128, 0, stream>>>(edge, fWe, fW1, cb1, cW2, cb2, ME, ADJ);
    for (int l = 0; l < P_; ++l) {
        k_xw<<<dim3(384, 4), 64, 0, stream>>>(HNb, fWh, XW);
        if (l < P_ - 1)
            k_fused<true><<<BTN_ / 2, 256, 0, stream>>>(ME, XW, cmb, fW1, cb1, cW2, cb2,
                                                        nnr, ADJ, MVb);
        else
            k_fused<false><<<BTN_ / 2, 256, 0, stream>>>(ME, XW, cmb, fW1, cb1, cW2, cb2,
                                                         nnr, ADJ, MVb);
        k_gruM<<<dim3(384, 4), 64, 0, stream>>>(MVb, HNb, HN, HNb, fgWih, fgWhh, cgbih, cgbhh, nnr);
    }
    k_gi<<<dim3(384, 8), 64, 0, stream>>>(HNb, flsWih, clsbih, clsbhh, GI);
    k_rec<<<12, 512, 0, stream>>>(GI, flsWhh, OUTH);
    k_readout<<<144, 256, 0, stream>>>(OUTH, croW, crob, nnr, (float*)d_out);
}

// Round 13
// 292.598 us; speedup vs baseline: 1.1099x; 1.0739x over previous
//
#include <hip/hip_runtime.h>
#include <cmath>

typedef unsigned short u16;
typedef unsigned int   u32;
typedef short bf16x8 __attribute__((ext_vector_type(8)));
typedef float f32x4 __attribute__((ext_vector_type(4)));

// Problem constants
constexpr int B_ = 8, T_ = 32, N_ = 24, D_ = 128;
constexpr int BT_ = B_ * T_;            // 256
constexpr int VW_ = N_ * N_;            // 576
constexpr int BTN_ = BT_ * N_;          // 6144
constexpr int BTVW_ = BT_ * VW_;        // 147456
constexpr int P_ = 3;
constexpr int C_ = 6;
constexpr int SA_ = 136;                // k_fused A row stride (u16); /2=68 u32

__device__ __forceinline__ float bits2f(u32 u) { float f; __builtin_memcpy(&f, &u, 4); return f; }
__device__ __forceinline__ float bf2f(u16 h) { return bits2f(((u32)h) << 16); }
__device__ __forceinline__ u16 f2bf(float f) {
    u32 u; __builtin_memcpy(&u, &f, 4);
    u32 r = u + 0x7FFFu + ((u >> 16) & 1u);
    return (u16)(r >> 16);
}
__device__ __forceinline__ f32x4 ld4bf(const u16* p) {
    const uint2 v = *(const uint2*)p;
    f32x4 r;
    r[0] = bf2f((u16)v.x); r[1] = bf2f((u16)(v.x >> 16));
    r[2] = bf2f((u16)v.y); r[3] = bf2f((u16)(v.y >> 16));
    return r;
}
// Fast activations via hardware v_exp_f32 / v_rcp_f32 (error ~1e-6).
__device__ __forceinline__ float fexp2(float x) { return __builtin_amdgcn_exp2f(x); }
__device__ __forceinline__ float frcp(float x) { return __builtin_amdgcn_rcpf(x); }
__device__ __forceinline__ float sigm(float x) {
    return frcp(1.0f + fexp2(x * -1.4426950408889634f));
}
__device__ __forceinline__ float ftanh(float x) {
    const float t = fexp2(fabsf(x) * -2.8853900817779268f);
    return copysignf((1.0f - t) * frcp(1.0f + t), x);
}

// ---------------------------------------------------------------------------
// Merged preprocessing: node transpose (blocks 0..255) + fragment-linear
// weight repack (blocks 256..1343) + small-array bf16 convert (1344..1355).
// ---------------------------------------------------------------------------
struct PreArgs {
    const float* node; float* HN; u16* HNb;
    const float* fsrc[7]; u16* fdst[7]; int fstart[8];
    const void* csrc[10]; u16* cdst[10]; int cstart[11];
};

__global__ __launch_bounds__(256) void k_preproc(PreArgs a) {
    const int bx = blockIdx.x;
    if (bx < 256) {
        const int bt = bx;
        for (int f = threadIdx.x; f < 3072; f += 256) {
            const int d = f / 24, n = f - d * 24;
            const float v = a.node[(size_t)bt * 3072 + f];
            a.HN[(size_t)bt * 3072 + n * 128 + d] = v;
            a.HNb[(size_t)bt * 3072 + n * 128 + d] = f2bf(v);
        }
    } else if (bx < 1344) {
        // FL[((rb*4+ks)*64 + lane)*8 + e] = W[(rb*16+m)*128 + ks*32 + quad*8 + e]
        const int idx = (bx - 256) * 256 + threadIdx.x;
        if (idx >= a.fstart[7]) return;
        int s = 0;
#pragma unroll
        for (int i = 1; i < 7; ++i) s += (idx >= a.fstart[i]) ? 1 : 0;
        const int off = idx - a.fstart[s];
        const int e = off & 7, lane = (off >> 3) & 63;
        const int ks = (off >> 9) & 3, rb = off >> 11;
        const int m = lane & 15, quad = lane >> 4;
        a.fdst[s][off] = f2bf(a.fsrc[s][(size_t)(rb * 16 + m) * 128 + ks * 32 + quad * 8 + e]);
    } else {
        const int idx = (bx - 1344) * 256 + threadIdx.x;
        if (idx >= a.cstart[10]) return;
        int s = 0;
#pragma unroll
        for (int i = 1; i < 10; ++i) s += (idx >= a.cstart[i]) ? 1 : 0;
        const int off = idx - a.cstart[s];
        a.cdst[s][off] = f2bf(((const float*)a.csrc[s])[off]);
    }
}

// ---------------------------------------------------------------------------
// k_prep: fused edge transpose + ME GEMM + layer-0 link-MLP.
// TWO waves per 32-row tile. DATA-DEPENDENT SKIP: tiles whose entire
// v-range is >= nv produce only values that downstream guards (vva &&
// w<nv) never consume -> skip the whole block (~46% expected, nnr~U[2,24]).
// ---------------------------------------------------------------------------
__global__ __launch_bounds__(128) void k_prep(
    const float* __restrict__ edge, const u16* __restrict__ WeF,
    const u16* __restrict__ W1F, const u16* __restrict__ b1,
    const u16* __restrict__ W2, const u16* __restrict__ b2,
    const int* __restrict__ nnr,
    u16* __restrict__ ME, float* __restrict__ ADJ) {
    __shared__ __align__(16) u16 A[32 * 128];   // swizzled, 8 KB
    const int tid = threadIdx.x;                // 0..127
    const int bt = blockIdx.x / 18, tile = blockIdx.x % 18;
    const int vw0 = tile * 32;
    // Block-uniform skip: all rows have v = (vw0+r)/24 >= nv -> all outputs
    // dead (consumed only under v<nv && w<nv guards downstream).
    if (vw0 >= nnr[bt] * 24) return;
    const size_t ebase = (size_t)bt * D_ * VW_ + vw0;
    // ---- staging: 8 float4 loads/lane across 128 threads ----
    const int vq = tid & 7, dg = tid >> 3;      // vq: vw-quad (8), dg: d-pair group (16)
    u32* A32 = (u32*)A;
    {
        float4 fa[4], fb[4];
#pragma unroll
        for (int it = 0; it < 4; ++it) {
            const int d0 = it * 32 + dg * 2;
            fa[it] = *(const float4*)&edge[ebase + (size_t)d0 * VW_ + vq * 4];
            fb[it] = *(const float4*)&edge[ebase + (size_t)(d0 + 1) * VW_ + vq * 4];
        }
#pragma unroll
        for (int it = 0; it < 4; ++it) {
            const int d0 = it * 32 + dg * 2;
            const float* pa = (const float*)&fa[it];
            const float* pb = (const float*)&fb[it];
#pragma unroll
            for (int i = 0; i < 4; ++i) {
                const int row = vq * 4 + i;
                const int sw32 = ((row >> 2) & 7) * 4;
                A32[row * 64 + ((d0 >> 1) ^ sw32)] =
                    (u32)f2bf(pa[i]) | ((u32)f2bf(pb[i]) << 16);
            }
        }
    }
    __syncthreads();
    const int wv = tid >> 6, lane = tid & 63;
    const int m = lane & 15, quad = lane >> 4;
    bf16x8 a[2][4];
#pragma unroll
    for (int rt = 0; rt < 2; ++rt) {
        const int row = rt * 16 + m;
        const int sw16 = ((row >> 2) & 7) * 8;
#pragma unroll
        for (int ks = 0; ks < 4; ++ks)
            a[rt][ks] = *(const bf16x8*)&A[row * 128 + ((ks * 32 + quad * 8) ^ sw16)];
    }
    const f32x4 z = {0.f, 0.f, 0.f, 0.f};
    if (wv == 0) {
        // ---- ME = A @ We^T (swapped operands -> coalesced uint2 stores) ----
#pragma unroll
        for (int ct = 0; ct < 8; ++ct) {
            bf16x8 bw[4];
#pragma unroll
            for (int ks = 0; ks < 4; ++ks)
                bw[ks] = *(const bf16x8*)&WeF[((ct * 4 + ks) << 9) + lane * 8];
            f32x4 acc[2];
#pragma unroll
            for (int rt = 0; rt < 2; ++rt) acc[rt] = z;
#pragma unroll
            for (int rt = 0; rt < 2; ++rt)
#pragma unroll
                for (int ks = 0; ks < 4; ++ks)
                    acc[rt] = __builtin_amdgcn_mfma_f32_16x16x32_bf16(bw[ks], a[rt][ks], acc[rt], 0, 0, 0);
#pragma unroll
            for (int rt = 0; rt < 2; ++rt) {
                const u32 lo = (u32)f2bf(acc[rt][0]) | ((u32)f2bf(acc[rt][1]) << 16);
                const u32 hi = (u32)f2bf(acc[rt][2]) | ((u32)f2bf(acc[rt][3]) << 16);
                *(uint2*)&ME[(size_t)(bt * VW_ + vw0 + rt * 16 + m) * 128 + ct * 16 + quad * 4] =
                    make_uint2(lo, hi);
            }
        }
    } else {
        // ---- layer-0 adjacency: relu(W1@A + b1) . W2 + b2 ----
        float p[2][4] = {};
        const float b2v = bf2f(b2[0]);
#pragma unroll
        for (int ct = 0; ct < 8; ++ct) {
            bf16x8 bw[4];
#pragma unroll
            for (int ks = 0; ks < 4; ++ks)
                bw[ks] = *(const bf16x8*)&W1F[((ct * 4 + ks) << 9) + lane * 8];
            f32x4 acc[2];
#pragma unroll
            for (int rt = 0; rt < 2; ++rt) acc[rt] = z;
#pragma unroll
            for (int rt = 0; rt < 2; ++rt)
#pragma unroll
                for (int ks = 0; ks < 4; ++ks)
                    acc[rt] = __builtin_amdgcn_mfma_f32_16x16x32_bf16(a[rt][ks], bw[ks], acc[rt], 0, 0, 0);
            const int n = ct * 16 + m;
            const float b1v = bf2f(b1[n]);
            const float w2v = bf2f(W2[n]);
#pragma unroll
            for (int rt = 0; rt < 2; ++rt)
#pragma unroll
                for (int reg = 0; reg < 4; ++reg)
                    p[rt][reg] += fmaxf(acc[rt][reg] + b1v, 0.0f) * w2v;
        }
#pragma unroll
        for (int rt = 0; rt < 2; ++rt)
#pragma unroll
            for (int reg = 0; reg < 4; ++reg) {
                float v = p[rt][reg];
                v += __shfl_xor(v, 1);
                v += __shfl_xor(v, 2);
                v += __shfl_xor(v, 4);
                v += __shfl_xor(v, 8);
                p[rt][reg] = v;
            }
        if (m == 0) {
#pragma unroll
            for (int rt = 0; rt < 2; ++rt)
#pragma unroll
                for (int reg = 0; reg < 4; ++reg)
                    ADJ[bt * VW_ + vw0 + rt * 16 + quad * 4 + reg] = p[rt][reg] + b2v;
        }
    }
}

// ---------------------------------------------------------------------------
// Fused per-(bt, v-pair) edge kernel. DATA-DEPENDENT SKIP: blocks with
// v0 >= nv write only dead values (MVb rows masked by `valid` in k_gruM,
// ADJ rows guarded next layer) -> uniform early exit before any barrier.
// ---------------------------------------------------------------------------
template <bool ADJP>
__global__ __launch_bounds__(256) void k_fused(
    const u16* __restrict__ ME, const float* __restrict__ XW,
    const u16* __restrict__ mb,
    const u16* __restrict__ W1F, const u16* __restrict__ b1,
    const u16* __restrict__ W2, const u16* __restrict__ b2,
    const int* __restrict__ nnr, float* __restrict__ ADJ,
    u16* __restrict__ MVb) {
    __shared__ __align__(16) u16 A[48 * SA_];
    __shared__ float gate_s[48];
    __shared__ float2 mvp[2][2][64];
    const int tid = threadIdx.x;
    const int blk = blockIdx.x;
    const int bt = blk / 12, pr = blk - bt * 12;
    const int v0 = pr * 2;
    const int e0 = bt * VW_ + v0 * N_;
    const int nv = nnr[bt];
    if (v0 >= nv) return;                 // block-uniform: all outputs dead

    if (tid < 48) gate_s[tid] = sigm(ADJ[e0 + tid]);
    __syncthreads();
    {
        const int op = tid & 63;
        const int sub = (tid >> 6) & 1;
        const int grp = tid >> 7;
        const int v = v0 + grp;
        const u32 mbu = ((const u32*)mb)[op];
        const float mb0 = bf2f((u16)mbu), mb1 = bf2f((u16)(mbu >> 16));
        const bool vva = v < nv;
        u32 meR[12]; float2 xwR[12];
#pragma unroll
        for (int i = 0; i < 12; ++i) {
            const int w = sub * 12 + i;
            const int rr = grp * 24 + w;
            meR[i] = ((const u32*)ME)[(size_t)(e0 + rr) * 64 + op];
            xwR[i] = *(const float2*)&XW[(size_t)(bt * N_ + w) * 128 + 2 * op];
        }
        float mvx = 0.0f, mvy = 0.0f;
        u32* A32 = (u32*)A;
#pragma unroll
        for (int i = 0; i < 12; ++i) {
            const int w = sub * 12 + i;
            const int rr = grp * 24 + w;
            float v0f = 0.0f, v1f = 0.0f;
            if (vva && w < nv) {
                const float g = gate_s[rr];
                v0f = g * fmaxf(xwR[i].x + bf2f((u16)meR[i]) + mb0, 0.0f);
                v1f = g * fmaxf(xwR[i].y + bf2f((u16)(meR[i] >> 16)) + mb1, 0.0f);
                mvx += v0f; mvy += v1f;
            }
            if (ADJP) A32[rr * 68 + op] = (u32)f2bf(v0f) | ((u32)f2bf(v1f) << 16);
        }
        mvp[grp][sub][op] = make_float2(mvx, mvy);
    }
    __syncthreads();
    if (tid < 128) {
        const int g2 = tid >> 6, o2 = tid & 63;
        const float2 pa = mvp[g2][0][o2], pb = mvp[g2][1][o2];
        ((u32*)MVb)[(size_t)(bt * N_ + v0 + g2) * 64 + o2] =
            (u32)f2bf(pa.x + pb.x) | ((u32)f2bf(pa.y + pb.y) << 16);
    }

    if constexpr (ADJP) {
        __syncthreads();
        if (tid >= 64) return;
        const int m = tid & 15, quad = tid >> 4;
        bf16x8 a[3][4];
#pragma unroll
        for (int rt = 0; rt < 3; ++rt)
#pragma unroll
            for (int ks = 0; ks < 4; ++ks)
                a[rt][ks] = *(const bf16x8*)&A[(rt * 16 + m) * SA_ + ks * 32 + quad * 8];
        const f32x4 z = {0.f, 0.f, 0.f, 0.f};
        float p[3][4] = {};
        const float b2v = bf2f(b2[0]);
#pragma unroll
        for (int ct = 0; ct < 8; ++ct) {
            bf16x8 bw[4];
#pragma unroll
            for (int ks = 0; ks < 4; ++ks)
                bw[ks] = *(const bf16x8*)&W1F[((ct * 4 + ks) << 9) + tid * 8];
            f32x4 acc[3];
#pragma unroll
            for (int rt = 0; rt < 3; ++rt) acc[rt] = z;
#pragma unroll
            for (int rt = 0; rt < 3; ++rt)
#pragma unroll
                for (int ks = 0; ks < 4; ++ks)
                    acc[rt] = __builtin_amdgcn_mfma_f32_16x16x32_bf16(a[rt][ks], bw[ks], acc[rt], 0, 0, 0);
            const int n = ct * 16 + m;
            const float b1v = bf2f(b1[n]);
            const float w2v = bf2f(W2[n]);
#pragma unroll
            for (int rt = 0; rt < 3; ++rt)
#pragma unroll
                for (int reg = 0; reg < 4; ++reg)
                    p[rt][reg] += fmaxf(acc[rt][reg] + b1v, 0.0f) * w2v;
        }
#pragma unroll
        for (int rt = 0; rt < 3; ++rt)
#pragma unroll
            for (int reg = 0; reg < 4; ++reg) {
                float v = p[rt][reg];
                v += __shfl_xor(v, 1);
                v += __shfl_xor(v, 2);
                v += __shfl_xor(v, 4);
                v += __shfl_xor(v, 8);
                p[rt][reg] = v;
            }
        if (m == 0) {
#pragma unroll
            for (int rt = 0; rt < 3; ++rt)
#pragma unroll
                for (int reg = 0; reg < 4; ++reg)
                    ADJ[e0 + rt * 16 + quad * 4 + reg] = p[rt][reg] + b2v;
        }
    }
}

// ---------------------------------------------------------------------------
// XW = HNb @ msg_Wh^T. grid (384,4) x 64: 1 wave = 16 rows x 2 col-tiles.
// ---------------------------------------------------------------------------
__global__ __launch_bounds__(64, 1) void k_xw(const u16* __restrict__ HNb,
                                              const u16* __restrict__ WhF,
                                              float* __restrict__ XW) {
    const int tid = threadIdx.x;
    const int m = tid & 15, quad = tid >> 4;
    const int r0 = blockIdx.x * 16;
    const int ct0 = blockIdx.y * 2;
    bf16x8 a[4];
#pragma unroll
    for (int ks = 0; ks < 4; ++ks)
        a[ks] = *(const bf16x8*)&HNb[(size_t)(r0 + m) * 128 + ks * 32 + quad * 8];
    const f32x4 z = {0.f, 0.f, 0.f, 0.f};
#pragma unroll
    for (int cti = 0; cti < 2; ++cti) {
        const int ct = ct0 + cti;
        f32x4 acc = z;
#pragma unroll
        for (int ks = 0; ks < 4; ++ks) {
            const bf16x8 b = *(const bf16x8*)&WhF[((ct * 4 + ks) << 9) + tid * 8];
            acc = __builtin_amdgcn_mfma_f32_16x16x32_bf16(b, a[ks], acc, 0, 0, 0);
        }
        *(f32x4*)&XW[(size_t)(r0 + m) * 128 + ct * 16 + quad * 4] = acc;
    }
}

// ---------------------------------------------------------------------------
// Fused MFMA GRU. grid (384,4) x 64: 1 wave = 16 rows x 2 col-tiles.
// ---------------------------------------------------------------------------
__global__ __launch_bounds__(64, 1) void k_gruM(
    const u16* __restrict__ MVb, const u16* __restrict__ HNb_in,
    float* __restrict__ HN, u16* __restrict__ HNb,
    const u16* __restrict__ WihF, const u16* __restrict__ WhhF,
    const u16* __restrict__ bih, const u16* __restrict__ bhh,
    const int* __restrict__ nnr) {
    const int tid = threadIdx.x;
    const int m = tid & 15, quad = tid >> 4;
    const int rbase = blockIdx.x * 16;
    const int ct0 = blockIdx.y * 2;
    bf16x8 amv[4], ahn[4];
#pragma unroll
    for (int ks = 0; ks < 4; ++ks) {
        amv[ks] = *(const bf16x8*)&MVb[(size_t)(rbase + m) * 128 + ks * 32 + quad * 8];
        ahn[ks] = *(const bf16x8*)&HNb_in[(size_t)(rbase + m) * 128 + ks * 32 + quad * 8];
    }
    const int myrow = rbase + m;
    const int mybt = myrow / N_;
    const bool valid = (myrow - mybt * N_) < nnr[mybt];
    const f32x4 z = {0.f, 0.f, 0.f, 0.f};
#pragma unroll
    for (int cti = 0; cti < 2; ++cti) {
        const int ct = ct0 + cti;
        f32x4 gi[3], gh[3];
#pragma unroll
        for (int g = 0; g < 3; ++g) { gi[g] = z; gh[g] = z; }
#pragma unroll
        for (int g = 0; g < 3; ++g) {
            const int rb = g * 8 + ct;
#pragma unroll
            for (int ks = 0; ks < 4; ++ks) {
                const bf16x8 bi_f = *(const bf16x8*)&WihF[((rb * 4 + ks) << 9) + tid * 8];
                const bf16x8 bh_f = *(const bf16x8*)&WhhF[((rb * 4 + ks) << 9) + tid * 8];
                gi[g] = __builtin_amdgcn_mfma_f32_16x16x32_bf16(bi_f, amv[ks], gi[g], 0, 0, 0);
                gh[g] = __builtin_amdgcn_mfma_f32_16x16x32_bf16(bh_f, ahn[ks], gh[g], 0, 0, 0);
            }
        }
        const int col0 = ct * 16 + quad * 4;
        const f32x4 biR = ld4bf(&bih[col0]),       bhR = ld4bf(&bhh[col0]);
        const f32x4 biZ = ld4bf(&bih[128 + col0]), bhZ = ld4bf(&bhh[128 + col0]);
        const f32x4 biN = ld4bf(&bih[256 + col0]), bhN = ld4bf(&bhh[256 + col0]);
        const size_t oi = (size_t)myrow * 128 + col0;
        const f32x4 hold = *(const f32x4*)&HN[oi];
        f32x4 hv;
#pragma unroll
        for (int reg = 0; reg < 4; ++reg) {
            const float r  = sigm(gi[0][reg] + gh[0][reg] + biR[reg] + bhR[reg]);
            const float zz = sigm(gi[1][reg] + gh[1][reg] + biZ[reg] + bhZ[reg]);
            const float nn = ftanh(gi[2][reg] + biN[reg] + r * (gh[2][reg] + bhN[reg]));
            hv[reg] = valid ? ((1.0f - zz) * nn + zz * hold[reg]) : 0.0f;
        }
        *(f32x4*)&HN[oi] = hv;
        const u32 lo = (u32)f2bf(hv[0]) | ((u32)f2bf(hv[1]) << 16);
        const u32 hi = (u32)f2bf(hv[2]) | ((u32)f2bf(hv[3]) << 16);
        *(uint2*)&HNb[oi] = make_uint2(lo, hi);
    }
}

// ---------------------------------------------------------------------------
// GI2 = HNb @ lstm_Wih^T + (bih+bhh) in k_rec's MFMA-lane layout.
// grid (384,8) x 64: 1 wave = 16 rows x 4 col-tiles.
// ---------------------------------------------------------------------------
__global__ __launch_bounds__(64, 2) void k_gi(const u16* __restrict__ HNb,
                                              const u16* __restrict__ WF,
                                              const u16* __restrict__ bih, const u16* __restrict__ bhh,
                                              float* __restrict__ GI2) {
    const int tid = threadIdx.x;
    const int m = tid & 15, quad = tid >> 4;
    const int r0 = blockIdx.x * 16;
    const int ocol0 = blockIdx.y * 64;
    const int r = r0 + m;
    const int btq = r / 24, n = r - btq * 24;
    const int b = btq >> 5, t = btq & 31;
    const int q = b * 24 + n;
    const int blk = q >> 4, mrow = q & 15;
    bf16x8 a[4];
#pragma unroll
    for (int ks = 0; ks < 4; ++ks)
        a[ks] = *(const bf16x8*)&HNb[(size_t)r * 128 + ks * 32 + quad * 8];
    const f32x4 z = {0.f, 0.f, 0.f, 0.f};
#pragma unroll
    for (int ct = 0; ct < 4; ++ct) {
        f32x4 acc = z;
        const int rb = blockIdx.y * 4 + ct;
#pragma unroll
        for (int ks = 0; ks < 4; ++ks) {
            const bf16x8 bb = *(const bf16x8*)&WF[((rb * 4 + ks) << 9) + tid * 8];
            acc = __builtin_amdgcn_mfma_f32_16x16x32_bf16(bb, a[ks], acc, 0, 0, 0);
        }
        const int col0 = ocol0 + ct * 16 + quad * 4;
        const f32x4 bi4 = ld4bf(&bih[col0]);
        const f32x4 bh4 = ld4bf(&bhh[col0]);
#pragma unroll
        for (int reg = 0; reg < 4; ++reg) acc[reg] += bi4[reg] + bh4[reg];
        const int cta = (ocol0 >> 4) + ct;      // 0..31
        const int w = cta & 7, j = cta >> 3;
        const size_t addr = ((size_t)(blk * 32 + t) * 512 + (w * 64 + quad * 16 + mrow)) * 16 + j * 4;
        *(f32x4*)&GI2[addr] = acc;
    }
}

// ---------------------------------------------------------------------------
// Recurrent LSTM via MFMA. 12 blocks x 512 threads (8 waves), 16 rows/block.
// ---------------------------------------------------------------------------
__global__ __launch_bounds__(512) void k_rec(const float* __restrict__ GI2,
                                             const u16* __restrict__ WhhF,
                                             float* __restrict__ OUTH) {
    __shared__ __align__(16) u16 Abuf[2][16 * 128];
    const int tid = threadIdx.x;
    const int w = tid >> 6, lane = tid & 63;
    const int m = lane & 15, quad = lane >> 4;
    const int blk = blockIdx.x;             // 0..11
    const int q = blk * 16 + m;             // global row b*24+n
    bf16x8 bw[4][4];
#pragma unroll
    for (int j = 0; j < 4; ++j)
#pragma unroll
        for (int ks = 0; ks < 4; ++ks)
            bw[j][ks] = *(const bf16x8*)&WhhF[(((j * 8 + w) * 4 + ks) << 9) + lane * 8];
    const f32x4 z = {0.f, 0.f, 0.f, 0.f};
    f32x4 cst = z;
    bf16x8 a[4];
#pragma unroll
    for (int ks = 0; ks < 4; ++ks) a[ks] = (bf16x8)(short)0;   // h0 = 0
    const float* gb = GI2 + ((size_t)blk * 32 * 512 + tid) * 16;
    f32x4 g[4], gn[4];
#pragma unroll
    for (int j = 0; j < 4; ++j) g[j] = *(const f32x4*)&gb[j * 4];
    const int ws = w * 2 + (quad >> 1);
    const int woff = (quad & 1) * 2;
    for (int t = 0; t < T_; ++t) {
        const int tn = (t + 1 < T_) ? (t + 1) : (T_ - 1);
        const size_t gnb = (size_t)tn * 512 * 16;
#pragma unroll
        for (int j = 0; j < 4; ++j) gn[j] = *(const f32x4*)&gb[gnb + j * 4];
        f32x4 acc[4];
#pragma unroll
        for (int j = 0; j < 4; ++j) acc[j] = z;
#pragma unroll
        for (int j = 0; j < 4; ++j)
#pragma unroll
            for (int ks = 0; ks < 4; ++ks)
                acc[j] = __builtin_amdgcn_mfma_f32_16x16x32_bf16(bw[j][ks], a[ks], acc[j], 0, 0, 0);
        f32x4 hv;
#pragma unroll
        for (int r = 0; r < 4; ++r) {
            const float gi_ = acc[0][r] + g[0][r];
            const float gf_ = acc[1][r] + g[1][r];
            const float gg_ = acc[2][r] + g[2][r];
            const float go_ = acc[3][r] + g[3][r];
            cst[r] = sigm(gf_) * cst[r] + sigm(gi_) * ftanh(gg_);
            hv[r] = sigm(go_) * ftanh(cst[r]);
        }
        *(f32x4*)&OUTH[((size_t)t * 192 + q) * 128 + w * 16 + quad * 4] = hv;
        const u32 lo = (u32)f2bf(hv[0]) | ((u32)f2bf(hv[1]) << 16);
        const u32 hi = (u32)f2bf(hv[2]) | ((u32)f2bf(hv[3]) << 16);
        u32* dst = (u32*)&Abuf[(t + 1) & 1][0];
        *(uint2*)&dst[m * 64 + ((ws ^ m) << 2) + woff] = make_uint2(lo, hi);
        __syncthreads();
        const u16* src = &Abuf[(t + 1) & 1][0];
#pragma unroll
        for (int ks = 0; ks < 4; ++ks)
            a[ks] = *(const bf16x8*)&src[m * 128 + (((ks * 4 + quad) ^ m) << 3)];
#pragma unroll
        for (int j = 0; j < 4; ++j) g[j] = gn[j];
    }
}

// ---------------------------------------------------------------------------
// Readout: out[b,t,n,c] = mask ? OUTH_row . ro_W[c] + ro_b[c] : 0   (fp32 out)
// ---------------------------------------------------------------------------
__global__ __launch_bounds__(256) void k_readout(const float* __restrict__ OUTH,
                                                 const u16* __restrict__ roW,
                                                 const u16* __restrict__ rob,
                                                 const int* __restrict__ nnr,
                                                 float* __restrict__ out) {
    const int idx = blockIdx.x * 256 + threadIdx.x;
    const int btn = idx / C_, c = idx - btn * C_;
    const int bt = btn / N_, n = btn - bt * N_;
    const int b = bt / T_, t = bt - b * T_;
    const int nv = nnr[bt];
    float val = 0.0f;
    if (n < nv) {
        const float* hrow = OUTH + ((size_t)t * 192 + b * N_ + n) * 128;
        const uint2* w2 = (const uint2*)&roW[c * 128];
        float acc = bf2f(rob[c]);
#pragma unroll
        for (int k4 = 0; k4 < 32; ++k4) {
            const float4 h4 = *(const float4*)&hrow[k4 * 4];
            const uint2 ww = w2[k4];
            acc = fmaf(bf2f((u16)ww.x), h4.x,
                  fmaf(bf2f((u16)(ww.x >> 16)), h4.y,
                  fmaf(bf2f((u16)ww.y), h4.z,
                  fmaf(bf2f((u16)(ww.y >> 16)), h4.w, acc))));
        }
        val = acc;
    }
    out[idx] = val;
}

// ---------------------------------------------------------------------------
extern "C" void kernel_launch(void* const* d_in, const int* in_sizes, int n_in,
                              void* d_out, int out_size, void* d_ws, size_t ws_size,
                              hipStream_t stream) {
    const float* node = (const float*)d_in[0];
    const float* edge = (const float*)d_in[1];
    const int* nnr = (const int*)d_in[19];

    // Workspace layout (~62 MB)
    char* ws = (char*)d_ws;
    float* HN = (float*)ws;   ws += (size_t)BTN_ * D_ * 4;    // 3.15 MB
    u16* HNb = (u16*)ws;      ws += (size_t)BTN_ * D_ * 2;    // 1.57 MB
    float* XW = (float*)ws;   ws += (size_t)BTN_ * D_ * 4;    // 3.15 MB
    u16* MVb = (u16*)ws;      ws += (size_t)BTN_ * D_ * 2;    // 1.57 MB
    float* ADJ = (float*)ws;  ws += (size_t)BTVW_ * 4;        // 0.59 MB
    float* GI = (float*)ws;   ws += (size_t)BTN_ * 512 * 4;   // 12.58 MB (GI2 layout)
    u16* WThh = (u16*)ws;     ws += 65536 * 2;                // 0.13 MB (unused, kept)
    u16* ME = (u16*)ws;       ws += (size_t)BTVW_ * D_ * 2;   // 37.75 MB
    float* OUTH = XW;         // XW dead after last k_fused; same size

    // Weight slots (same 17-slot layout; the 7 big ones hold FRAGMENT-LINEAR
    // bf16; the 10 small ones canonical bf16) — all written by k_preproc.
    u16* cbase = (u16*)ws;
    const int cvtN17[17] = {16384, 128, 128, 1, 16384, 16384, 128,
                            49152, 49152, 384, 384, 65536, 65536, 512, 512, 768, 6};
    u16* cptr[17];
    {
        int off = 0;
        for (int i = 0; i < 17; ++i) {
            cptr[i] = cbase + off;
            off += (cvtN17[i] + 7) & ~7;
        }
    }
    PreArgs pa;
    pa.node = node; pa.HN = HN; pa.HNb = HNb;
    {
        const int din_idx[7] = {2, 6, 7, 9, 10, 13, 14};
        const int slot[7]    = {0, 4, 5, 7,  8, 11, 12};
        const int nelem[7]   = {16384, 16384, 16384, 49152, 49152, 65536, 65536};
        int cum = 0;
        for (int i = 0; i < 7; ++i) {
            pa.fsrc[i] = (const float*)d_in[din_idx[i]];
            pa.fdst[i] = cptr[slot[i]];
            pa.fstart[i] = cum;
            cum += nelem[i];
        }
        pa.fstart[7] = cum;             // 278528 = 1088 * 256
    }
    {
        const int din_idx[10] = {3, 4, 5, 8, 11, 12, 15, 16, 17, 18};
        const int slot[10]    = {1, 2, 3, 6,  9, 10, 13, 14, 15, 16};
        const int nelem[10]   = {128, 128, 1, 128, 384, 384, 512, 512, 768, 6};
        int cum = 0;
        for (int i = 0; i < 10; ++i) {
            pa.csrc[i] = d_in[din_idx[i]];
            pa.cdst[i] = cptr[slot[i]];
            pa.cstart[i] = cum;
            cum += nelem[i];
        }
        pa.cstart[10] = cum;            // 2951
    }
    u16* fW1 = cptr[0];  u16* cb1 = cptr[1];  u16* cW2 = cptr[2];  u16* cb2 = cptr[3];
    u16* fWh = cptr[4];  u16* fWe = cptr[5];  u16* cmb = cptr[6];
    u16* fgWih = cptr[7]; u16* fgWhh = cptr[8]; u16* cgbih = cptr[9]; u16* cgbhh = cptr[10];
    u16* flsWih = cptr[11]; u16* flsWhh = cptr[12]; u16* clsbih = cptr[13]; u16* clsbhh = cptr[14];
    u16* croW = cptr[15]; u16* crob = cptr[16];
    (void)WThh;

    k_preproc<<<1356, 256, 0, stream>>>(pa);
    k_prep<<<BT_ * 18, 128, 0, stream>>>(edge, fWe, fW1, cb1, cW2, cb2, nnr, ME, ADJ);
    for (int l = 0; l < P_; ++l) {
        k_xw<<<dim3(384, 4), 64, 0, stream>>>(HNb, fWh, XW);
        if (l < P_ - 1)
            k_fused<true><<<BTN_ / 2, 256, 0, stream>>>(ME, XW, cmb, fW1, cb1, cW2, cb2,
                                                        nnr, ADJ, MVb);
        else
            k_fused<false><<<BTN_ / 2, 256, 0, stream>>>(ME, XW, cmb, fW1, cb1, cW2, cb2,
                                                         nnr, ADJ, MVb);
        k_gruM<<<dim3(384, 4), 64, 0, stream>>>(MVb, HNb, HN, HNb, fgWih, fgWhh, cgbih, cgbhh, nnr);
    }
    k_gi<<<dim3(384, 8), 64, 0, stream>>>(HNb, flsWih, clsbih, clsbhh, GI);
    k_rec<<<12, 512, 0, stream>>>(GI, flsWhh, OUTH);
    k_readout<<<144, 256, 0, stream>>>(OUTH, croW, crob, nnr, (float*)d_out);
}

// Round 14
// 287.460 us; speedup vs baseline: 1.1298x; 1.0179x over previous
//
#include <hip/hip_runtime.h>
#include <cmath>

typedef unsigned short u16;
typedef unsigned int   u32;
typedef short bf16x8 __attribute__((ext_vector_type(8)));
typedef float f32x4 __attribute__((ext_vector_type(4)));

// Problem constants
constexpr int B_ = 8, T_ = 32, N_ = 24, D_ = 128;
constexpr int BT_ = B_ * T_;            // 256
constexpr int VW_ = N_ * N_;            // 576
constexpr int BTN_ = BT_ * N_;          // 6144
constexpr int BTVW_ = BT_ * VW_;        // 147456
constexpr int P_ = 3;
constexpr int C_ = 6;
constexpr int SA_ = 136;                // k_fused A row stride (u16); /2=68 u32

__device__ __forceinline__ float bits2f(u32 u) { float f; __builtin_memcpy(&f, &u, 4); return f; }
__device__ __forceinline__ float bf2f(u16 h) { return bits2f(((u32)h) << 16); }
__device__ __forceinline__ u16 f2bf(float f) {
    u32 u; __builtin_memcpy(&u, &f, 4);
    u32 r = u + 0x7FFFu + ((u >> 16) & 1u);
    return (u16)(r >> 16);
}
__device__ __forceinline__ f32x4 ld4bf(const u16* p) {
    const uint2 v = *(const uint2*)p;
    f32x4 r;
    r[0] = bf2f((u16)v.x); r[1] = bf2f((u16)(v.x >> 16));
    r[2] = bf2f((u16)v.y); r[3] = bf2f((u16)(v.y >> 16));
    return r;
}
// Fast activations via hardware v_exp_f32 / v_rcp_f32 (error ~1e-6).
__device__ __forceinline__ float fexp2(float x) { return __builtin_amdgcn_exp2f(x); }
__device__ __forceinline__ float frcp(float x) { return __builtin_amdgcn_rcpf(x); }
__device__ __forceinline__ float sigm(float x) {
    return frcp(1.0f + fexp2(x * -1.4426950408889634f));
}
__device__ __forceinline__ float ftanh(float x) {
    const float t = fexp2(fabsf(x) * -2.8853900817779268f);
    return copysignf((1.0f - t) * frcp(1.0f + t), x);
}

// ---------------------------------------------------------------------------
// Merged preprocessing: node transpose (blocks 0..255) + fragment-linear
// weight repack (blocks 256..1343) + small-array bf16 convert (1344..1355).
// ---------------------------------------------------------------------------
struct PreArgs {
    const float* node; float* HN; u16* HNb;
    const float* fsrc[7]; u16* fdst[7]; int fstart[8];
    const void* csrc[10]; u16* cdst[10]; int cstart[11];
};

__global__ __launch_bounds__(256) void k_preproc(PreArgs a) {
    const int bx = blockIdx.x;
    if (bx < 256) {
        const int bt = bx;
        for (int f = threadIdx.x; f < 3072; f += 256) {
            const int d = f / 24, n = f - d * 24;
            const float v = a.node[(size_t)bt * 3072 + f];
            a.HN[(size_t)bt * 3072 + n * 128 + d] = v;
            a.HNb[(size_t)bt * 3072 + n * 128 + d] = f2bf(v);
        }
    } else if (bx < 1344) {
        // FL[((rb*4+ks)*64 + lane)*8 + e] = W[(rb*16+m)*128 + ks*32 + quad*8 + e]
        const int idx = (bx - 256) * 256 + threadIdx.x;
        if (idx >= a.fstart[7]) return;
        int s = 0;
#pragma unroll
        for (int i = 1; i < 7; ++i) s += (idx >= a.fstart[i]) ? 1 : 0;
        const int off = idx - a.fstart[s];
        const int e = off & 7, lane = (off >> 3) & 63;
        const int ks = (off >> 9) & 3, rb = off >> 11;
        const int m = lane & 15, quad = lane >> 4;
        a.fdst[s][off] = f2bf(a.fsrc[s][(size_t)(rb * 16 + m) * 128 + ks * 32 + quad * 8 + e]);
    } else {
        const int idx = (bx - 1344) * 256 + threadIdx.x;
        if (idx >= a.cstart[10]) return;
        int s = 0;
#pragma unroll
        for (int i = 1; i < 10; ++i) s += (idx >= a.cstart[i]) ? 1 : 0;
        const int off = idx - a.cstart[s];
        a.cdst[s][off] = f2bf(((const float*)a.csrc[s])[off]);
    }
}

// ---------------------------------------------------------------------------
// k_prep: fused edge transpose + ME GEMM + layer-0 link-MLP.
// TWO waves per 32-row tile. Block skip when tile fully dead (R13, proven);
// NEW: per-row ME/ADJ store guards for dead rows inside boundary tiles
// (consumed only under v<nv && w<nv guards downstream).
// ---------------------------------------------------------------------------
__global__ __launch_bounds__(128) void k_prep(
    const float* __restrict__ edge, const u16* __restrict__ WeF,
    const u16* __restrict__ W1F, const u16* __restrict__ b1,
    const u16* __restrict__ W2, const u16* __restrict__ b2,
    const int* __restrict__ nnr,
    u16* __restrict__ ME, float* __restrict__ ADJ) {
    __shared__ __align__(16) u16 A[32 * 128];   // swizzled, 8 KB
    const int tid = threadIdx.x;                // 0..127
    const int bt = blockIdx.x / 18, tile = blockIdx.x % 18;
    const int vw0 = tile * 32;
    const int nv24 = nnr[bt] * 24;
    if (vw0 >= nv24) return;                    // fully-dead tile
    const size_t ebase = (size_t)bt * D_ * VW_ + vw0;
    // ---- staging: 8 float4 loads/lane across 128 threads ----
    const int vq = tid & 7, dg = tid >> 3;      // vq: vw-quad (8), dg: d-pair group (16)
    u32* A32 = (u32*)A;
    {
        float4 fa[4], fb[4];
#pragma unroll
        for (int it = 0; it < 4; ++it) {
            const int d0 = it * 32 + dg * 2;
            fa[it] = *(const float4*)&edge[ebase + (size_t)d0 * VW_ + vq * 4];
            fb[it] = *(const float4*)&edge[ebase + (size_t)(d0 + 1) * VW_ + vq * 4];
        }
#pragma unroll
        for (int it = 0; it < 4; ++it) {
            const int d0 = it * 32 + dg * 2;
            const float* pa = (const float*)&fa[it];
            const float* pb = (const float*)&fb[it];
#pragma unroll
            for (int i = 0; i < 4; ++i) {
                const int row = vq * 4 + i;
                const int sw32 = ((row >> 2) & 7) * 4;
                A32[row * 64 + ((d0 >> 1) ^ sw32)] =
                    (u32)f2bf(pa[i]) | ((u32)f2bf(pb[i]) << 16);
            }
        }
    }
    __syncthreads();
    const int wv = tid >> 6, lane = tid & 63;
    const int m = lane & 15, quad = lane >> 4;
    bf16x8 a[2][4];
#pragma unroll
    for (int rt = 0; rt < 2; ++rt) {
        const int row = rt * 16 + m;
        const int sw16 = ((row >> 2) & 7) * 8;
#pragma unroll
        for (int ks = 0; ks < 4; ++ks)
            a[rt][ks] = *(const bf16x8*)&A[row * 128 + ((ks * 32 + quad * 8) ^ sw16)];
    }
    const f32x4 z = {0.f, 0.f, 0.f, 0.f};
    if (wv == 0) {
        // ---- ME = A @ We^T (swapped operands -> coalesced uint2 stores) ----
#pragma unroll
        for (int ct = 0; ct < 8; ++ct) {
            bf16x8 bw[4];
#pragma unroll
            for (int ks = 0; ks < 4; ++ks)
                bw[ks] = *(const bf16x8*)&WeF[((ct * 4 + ks) << 9) + lane * 8];
            f32x4 acc[2];
#pragma unroll
            for (int rt = 0; rt < 2; ++rt) acc[rt] = z;
#pragma unroll
            for (int rt = 0; rt < 2; ++rt)
#pragma unroll
                for (int ks = 0; ks < 4; ++ks)
                    acc[rt] = __builtin_amdgcn_mfma_f32_16x16x32_bf16(bw[ks], a[rt][ks], acc[rt], 0, 0, 0);
#pragma unroll
            for (int rt = 0; rt < 2; ++rt) {
                if (vw0 + rt * 16 + m < nv24) {     // dead-row store guard
                    const u32 lo = (u32)f2bf(acc[rt][0]) | ((u32)f2bf(acc[rt][1]) << 16);
                    const u32 hi = (u32)f2bf(acc[rt][2]) | ((u32)f2bf(acc[rt][3]) << 16);
                    *(uint2*)&ME[(size_t)(bt * VW_ + vw0 + rt * 16 + m) * 128 + ct * 16 + quad * 4] =
                        make_uint2(lo, hi);
                }
            }
        }
    } else {
        // ---- layer-0 adjacency: relu(W1@A + b1) . W2 + b2 ----
        float p[2][4] = {};
        const float b2v = bf2f(b2[0]);
#pragma unroll
        for (int ct = 0; ct < 8; ++ct) {
            bf16x8 bw[4];
#pragma unroll
            for (int ks = 0; ks < 4; ++ks)
                bw[ks] = *(const bf16x8*)&W1F[((ct * 4 + ks) << 9) + lane * 8];
            f32x4 acc[2];
#pragma unroll
            for (int rt = 0; rt < 2; ++rt) acc[rt] = z;
#pragma unroll
            for (int rt = 0; rt < 2; ++rt)
#pragma unroll
                for (int ks = 0; ks < 4; ++ks)
                    acc[rt] = __builtin_amdgcn_mfma_f32_16x16x32_bf16(a[rt][ks], bw[ks], acc[rt], 0, 0, 0);
            const int n = ct * 16 + m;
            const float b1v = bf2f(b1[n]);
            const float w2v = bf2f(W2[n]);
#pragma unroll
            for (int rt = 0; rt < 2; ++rt)
#pragma unroll
                for (int reg = 0; reg < 4; ++reg)
                    p[rt][reg] += fmaxf(acc[rt][reg] + b1v, 0.0f) * w2v;
        }
#pragma unroll
        for (int rt = 0; rt < 2; ++rt)
#pragma unroll
            for (int reg = 0; reg < 4; ++reg) {
                float v = p[rt][reg];
                v += __shfl_xor(v, 1);
                v += __shfl_xor(v, 2);
                v += __shfl_xor(v, 4);
                v += __shfl_xor(v, 8);
                p[rt][reg] = v;
            }
        if (m == 0) {
#pragma unroll
            for (int rt = 0; rt < 2; ++rt)
#pragma unroll
                for (int reg = 0; reg < 4; ++reg) {
                    const int row = vw0 + rt * 16 + quad * 4 + reg;
                    if (row < nv24)                 // dead-row store guard
                        ADJ[bt * VW_ + row] = p[rt][reg] + b2v;
                }
        }
    }
}

// ---------------------------------------------------------------------------
// Fused per-(bt, v-pair) edge kernel. Block skip when v0 >= nv (R13).
// NEW: meR/xwR loads predicated by the wave-uniform (vva && w<nv) guard —
// dead loads (mean 46%) never issue; consumed values unchanged.
// ---------------------------------------------------------------------------
template <bool ADJP>
__global__ __launch_bounds__(256) void k_fused(
    const u16* __restrict__ ME, const float* __restrict__ XW,
    const u16* __restrict__ mb,
    const u16* __restrict__ W1F, const u16* __restrict__ b1,
    const u16* __restrict__ W2, const u16* __restrict__ b2,
    const int* __restrict__ nnr, float* __restrict__ ADJ,
    u16* __restrict__ MVb) {
    __shared__ __align__(16) u16 A[48 * SA_];
    __shared__ float gate_s[48];
    __shared__ float2 mvp[2][2][64];
    const int tid = threadIdx.x;
    const int blk = blockIdx.x;
    const int bt = blk / 12, pr = blk - bt * 12;
    const int v0 = pr * 2;
    const int e0 = bt * VW_ + v0 * N_;
    const int nv = nnr[bt];
    if (v0 >= nv) return;                 // block-uniform: all outputs dead

    if (tid < 48) gate_s[tid] = sigm(ADJ[e0 + tid]);
    __syncthreads();
    {
        const int op = tid & 63;
        const int sub = (tid >> 6) & 1;
        const int grp = tid >> 7;
        const int v = v0 + grp;
        const u32 mbu = ((const u32*)mb)[op];
        const float mb0 = bf2f((u16)mbu), mb1 = bf2f((u16)(mbu >> 16));
        const bool vva = v < nv;
        u32 meR[12]; float2 xwR[12];
#pragma unroll
        for (int i = 0; i < 12; ++i) {
            const int w = sub * 12 + i;
            const int rr = grp * 24 + w;
            if (vva && w < nv) {          // wave-uniform predicated loads
                meR[i] = ((const u32*)ME)[(size_t)(e0 + rr) * 64 + op];
                xwR[i] = *(const float2*)&XW[(size_t)(bt * N_ + w) * 128 + 2 * op];
            } else {
                meR[i] = 0u;
                xwR[i] = make_float2(0.0f, 0.0f);
            }
        }
        float mvx = 0.0f, mvy = 0.0f;
        u32* A32 = (u32*)A;
#pragma unroll
        for (int i = 0; i < 12; ++i) {
            const int w = sub * 12 + i;
            const int rr = grp * 24 + w;
            float v0f = 0.0f, v1f = 0.0f;
            if (vva && w < nv) {
                const float g = gate_s[rr];
                v0f = g * fmaxf(xwR[i].x + bf2f((u16)meR[i]) + mb0, 0.0f);
                v1f = g * fmaxf(xwR[i].y + bf2f((u16)(meR[i] >> 16)) + mb1, 0.0f);
                mvx += v0f; mvy += v1f;
            }
            if (ADJP) A32[rr * 68 + op] = (u32)f2bf(v0f) | ((u32)f2bf(v1f) << 16);
        }
        mvp[grp][sub][op] = make_float2(mvx, mvy);
    }
    __syncthreads();
    if (tid < 128) {
        const int g2 = tid >> 6, o2 = tid & 63;
        const float2 pa = mvp[g2][0][o2], pb = mvp[g2][1][o2];
        ((u32*)MVb)[(size_t)(bt * N_ + v0 + g2) * 64 + o2] =
            (u32)f2bf(pa.x + pb.x) | ((u32)f2bf(pa.y + pb.y) << 16);
    }

    if constexpr (ADJP) {
        __syncthreads();
        if (tid >= 64) return;
        const int m = tid & 15, quad = tid >> 4;
        bf16x8 a[3][4];
#pragma unroll
        for (int rt = 0; rt < 3; ++rt)
#pragma unroll
            for (int ks = 0; ks < 4; ++ks)
                a[rt][ks] = *(const bf16x8*)&A[(rt * 16 + m) * SA_ + ks * 32 + quad * 8];
        const f32x4 z = {0.f, 0.f, 0.f, 0.f};
        float p[3][4] = {};
        const float b2v = bf2f(b2[0]);
#pragma unroll
        for (int ct = 0; ct < 8; ++ct) {
            bf16x8 bw[4];
#pragma unroll
            for (int ks = 0; ks < 4; ++ks)
                bw[ks] = *(const bf16x8*)&W1F[((ct * 4 + ks) << 9) + tid * 8];
            f32x4 acc[3];
#pragma unroll
            for (int rt = 0; rt < 3; ++rt) acc[rt] = z;
#pragma unroll
            for (int rt = 0; rt < 3; ++rt)
#pragma unroll
                for (int ks = 0; ks < 4; ++ks)
                    acc[rt] = __builtin_amdgcn_mfma_f32_16x16x32_bf16(a[rt][ks], bw[ks], acc[rt], 0, 0, 0);
            const int n = ct * 16 + m;
            const float b1v = bf2f(b1[n]);
            const float w2v = bf2f(W2[n]);
#pragma unroll
            for (int rt = 0; rt < 3; ++rt)
#pragma unroll
                for (int reg = 0; reg < 4; ++reg)
                    p[rt][reg] += fmaxf(acc[rt][reg] + b1v, 0.0f) * w2v;
        }
#pragma unroll
        for (int rt = 0; rt < 3; ++rt)
#pragma unroll
            for (int reg = 0; reg < 4; ++reg) {
                float v = p[rt][reg];
                v += __shfl_xor(v, 1);
                v += __shfl_xor(v, 2);
                v += __shfl_xor(v, 4);
                v += __shfl_xor(v, 8);
                p[rt][reg] = v;
            }
        if (m == 0) {
#pragma unroll
            for (int rt = 0; rt < 3; ++rt)
#pragma unroll
                for (int reg = 0; reg < 4; ++reg)
                    ADJ[e0 + rt * 16 + quad * 4 + reg] = p[rt][reg] + b2v;
        }
    }
}

// ---------------------------------------------------------------------------
// XW = HNb @ msg_Wh^T. grid (384,4) x 64. NEW: store guard for dead rows
// (n >= nv; xwR loads in k_fused are guarded by the same condition).
// ---------------------------------------------------------------------------
__global__ __launch_bounds__(64, 1) void k_xw(const u16* __restrict__ HNb,
                                              const u16* __restrict__ WhF,
                                              const int* __restrict__ nnr,
                                              float* __restrict__ XW) {
    const int tid = threadIdx.x;
    const int m = tid & 15, quad = tid >> 4;
    const int r0 = blockIdx.x * 16;
    const int ct0 = blockIdx.y * 2;
    const int myrow = r0 + m;
    const int mybt = myrow / N_;
    const bool rowlive = (myrow - mybt * N_) < nnr[mybt];
    bf16x8 a[4];
#pragma unroll
    for (int ks = 0; ks < 4; ++ks)
        a[ks] = *(const bf16x8*)&HNb[(size_t)myrow * 128 + ks * 32 + quad * 8];
    const f32x4 z = {0.f, 0.f, 0.f, 0.f};
#pragma unroll
    for (int cti = 0; cti < 2; ++cti) {
        const int ct = ct0 + cti;
        f32x4 acc = z;
#pragma unroll
        for (int ks = 0; ks < 4; ++ks) {
            const bf16x8 b = *(const bf16x8*)&WhF[((ct * 4 + ks) << 9) + tid * 8];
            acc = __builtin_amdgcn_mfma_f32_16x16x32_bf16(b, a[ks], acc, 0, 0, 0);
        }
        if (rowlive)
            *(f32x4*)&XW[(size_t)myrow * 128 + ct * 16 + quad * 4] = acc;
    }
}

// ---------------------------------------------------------------------------
// Fused MFMA GRU. grid (384,4) x 64. NEW: stores skipped for invalid rows —
// those rows are already 0 (masked init, stays 0 each layer) and hv would
// be 0; skipping the store leaves the same value.
// ---------------------------------------------------------------------------
__global__ __launch_bounds__(64, 1) void k_gruM(
    const u16* __restrict__ MVb, const u16* __restrict__ HNb_in,
    float* __restrict__ HN, u16* __restrict__ HNb,
    const u16* __restrict__ WihF, const u16* __restrict__ WhhF,
    const u16* __restrict__ bih, const u16* __restrict__ bhh,
    const int* __restrict__ nnr) {
    const int tid = threadIdx.x;
    const int m = tid & 15, quad = tid >> 4;
    const int rbase = blockIdx.x * 16;
    const int ct0 = blockIdx.y * 2;
    bf16x8 amv[4], ahn[4];
#pragma unroll
    for (int ks = 0; ks < 4; ++ks) {
        amv[ks] = *(const bf16x8*)&MVb[(size_t)(rbase + m) * 128 + ks * 32 + quad * 8];
        ahn[ks] = *(const bf16x8*)&HNb_in[(size_t)(rbase + m) * 128 + ks * 32 + quad * 8];
    }
    const int myrow = rbase + m;
    const int mybt = myrow / N_;
    const bool valid = (myrow - mybt * N_) < nnr[mybt];
    const f32x4 z = {0.f, 0.f, 0.f, 0.f};
#pragma unroll
    for (int cti = 0; cti < 2; ++cti) {
        const int ct = ct0 + cti;
        f32x4 gi[3], gh[3];
#pragma unroll
        for (int g = 0; g < 3; ++g) { gi[g] = z; gh[g] = z; }
#pragma unroll
        for (int g = 0; g < 3; ++g) {
            const int rb = g * 8 + ct;
#pragma unroll
            for (int ks = 0; ks < 4; ++ks) {
                const bf16x8 bi_f = *(const bf16x8*)&WihF[((rb * 4 + ks) << 9) + tid * 8];
                const bf16x8 bh_f = *(const bf16x8*)&WhhF[((rb * 4 + ks) << 9) + tid * 8];
                gi[g] = __builtin_amdgcn_mfma_f32_16x16x32_bf16(bi_f, amv[ks], gi[g], 0, 0, 0);
                gh[g] = __builtin_amdgcn_mfma_f32_16x16x32_bf16(bh_f, ahn[ks], gh[g], 0, 0, 0);
            }
        }
        const int col0 = ct * 16 + quad * 4;
        const f32x4 biR = ld4bf(&bih[col0]),       bhR = ld4bf(&bhh[col0]);
        const f32x4 biZ = ld4bf(&bih[128 + col0]), bhZ = ld4bf(&bhh[128 + col0]);
        const f32x4 biN = ld4bf(&bih[256 + col0]), bhN = ld4bf(&bhh[256 + col0]);
        const size_t oi = (size_t)myrow * 128 + col0;
        const f32x4 hold = *(const f32x4*)&HN[oi];
        f32x4 hv;
#pragma unroll
        for (int reg = 0; reg < 4; ++reg) {
            const float r  = sigm(gi[0][reg] + gh[0][reg] + biR[reg] + bhR[reg]);
            const float zz = sigm(gi[1][reg] + gh[1][reg] + biZ[reg] + bhZ[reg]);
            const float nn = ftanh(gi[2][reg] + biN[reg] + r * (gh[2][reg] + bhN[reg]));
            hv[reg] = (1.0f - zz) * nn + zz * hold[reg];
        }
        if (valid) {
            *(f32x4*)&HN[oi] = hv;
            const u32 lo = (u32)f2bf(hv[0]) | ((u32)f2bf(hv[1]) << 16);
            const u32 hi = (u32)f2bf(hv[2]) | ((u32)f2bf(hv[3]) << 16);
            *(uint2*)&HNb[oi] = make_uint2(lo, hi);
        }
    }
}

// ---------------------------------------------------------------------------
// GI2 = HNb @ lstm_Wih^T + (bih+bhh) in k_rec's MFMA-lane layout.
// grid (384,8) x 64: 1 wave = 16 rows x 4 col-tiles.
// ---------------------------------------------------------------------------
__global__ __launch_bounds__(64, 2) void k_gi(const u16* __restrict__ HNb,
                                              const u16* __restrict__ WF,
                                              const u16* __restrict__ bih, const u16* __restrict__ bhh,
                                              float* __restrict__ GI2) {
    const int tid = threadIdx.x;
    const int m = tid & 15, quad = tid >> 4;
    const int r0 = blockIdx.x * 16;
    const int ocol0 = blockIdx.y * 64;
    const int r = r0 + m;
    const int btq = r / 24, n = r - btq * 24;
    const int b = btq >> 5, t = btq & 31;
    const int q = b * 24 + n;
    const int blk = q >> 4, mrow = q & 15;
    bf16x8 a[4];
#pragma unroll
    for (int ks = 0; ks < 4; ++ks)
        a[ks] = *(const bf16x8*)&HNb[(size_t)r * 128 + ks * 32 + quad * 8];
    const f32x4 z = {0.f, 0.f, 0.f, 0.f};
#pragma unroll
    for (int ct = 0; ct < 4; ++ct) {
        f32x4 acc = z;
        const int rb = blockIdx.y * 4 + ct;
#pragma unroll
        for (int ks = 0; ks < 4; ++ks) {
            const bf16x8 bb = *(const bf16x8*)&WF[((rb * 4 + ks) << 9) + tid * 8];
            acc = __builtin_amdgcn_mfma_f32_16x16x32_bf16(bb, a[ks], acc, 0, 0, 0);
        }
        const int col0 = ocol0 + ct * 16 + quad * 4;
        const f32x4 bi4 = ld4bf(&bih[col0]);
        const f32x4 bh4 = ld4bf(&bhh[col0]);
#pragma unroll
        for (int reg = 0; reg < 4; ++reg) acc[reg] += bi4[reg] + bh4[reg];
        const int cta = (ocol0 >> 4) + ct;      // 0..31
        const int w = cta & 7, j = cta >> 3;
        const size_t addr = ((size_t)(blk * 32 + t) * 512 + (w * 64 + quad * 16 + mrow)) * 16 + j * 4;
        *(f32x4*)&GI2[addr] = acc;
    }
}

// ---------------------------------------------------------------------------
// Recurrent LSTM via MFMA. 12 blocks x 512 threads (8 waves), 16 rows/block.
// ---------------------------------------------------------------------------
__global__ __launch_bounds__(512) void k_rec(const float* __restrict__ GI2,
                                             const u16* __restrict__ WhhF,
                                             float* __restrict__ OUTH) {
    __shared__ __align__(16) u16 Abuf[2][16 * 128];
    const int tid = threadIdx.x;
    const int w = tid >> 6, lane = tid & 63;
    const int m = lane & 15, quad = lane >> 4;
    const int blk = blockIdx.x;             // 0..11
    const int q = blk * 16 + m;             // global row b*24+n
    bf16x8 bw[4][4];
#pragma unroll
    for (int j = 0; j < 4; ++j)
#pragma unroll
        for (int ks = 0; ks < 4; ++ks)
            bw[j][ks] = *(const bf16x8*)&WhhF[(((j * 8 + w) * 4 + ks) << 9) + lane * 8];
    const f32x4 z = {0.f, 0.f, 0.f, 0.f};
    f32x4 cst = z;
    bf16x8 a[4];
#pragma unroll
    for (int ks = 0; ks < 4; ++ks) a[ks] = (bf16x8)(short)0;   // h0 = 0
    const float* gb = GI2 + ((size_t)blk * 32 * 512 + tid) * 16;
    f32x4 g[4], gn[4];
#pragma unroll
    for (int j = 0; j < 4; ++j) g[j] = *(const f32x4*)&gb[j * 4];
    const int ws = w * 2 + (quad >> 1);
    const int woff = (quad & 1) * 2;
    for (int t = 0; t < T_; ++t) {
        const int tn = (t + 1 < T_) ? (t + 1) : (T_ - 1);
        const size_t gnb = (size_t)tn * 512 * 16;
#pragma unroll
        for (int j = 0; j < 4; ++j) gn[j] = *(const f32x4*)&gb[gnb + j * 4];
        f32x4 acc[4];
#pragma unroll
        for (int j = 0; j < 4; ++j) acc[j] = z;
#pragma unroll
        for (int j = 0; j < 4; ++j)
#pragma unroll
            for (int ks = 0; ks < 4; ++ks)
                acc[j] = __builtin_amdgcn_mfma_f32_16x16x32_bf16(bw[j][ks], a[ks], acc[j], 0, 0, 0);
        f32x4 hv;
#pragma unroll
        for (int r = 0; r < 4; ++r) {
            const float gi_ = acc[0][r] + g[0][r];
            const float gf_ = acc[1][r] + g[1][r];
            const float gg_ = acc[2][r] + g[2][r];
            const float go_ = acc[3][r] + g[3][r];
            cst[r] = sigm(gf_) * cst[r] + sigm(gi_) * ftanh(gg_);
            hv[r] = sigm(go_) * ftanh(cst[r]);
        }
        *(f32x4*)&OUTH[((size_t)t * 192 + q) * 128 + w * 16 + quad * 4] = hv;
        const u32 lo = (u32)f2bf(hv[0]) | ((u32)f2bf(hv[1]) << 16);
        const u32 hi = (u32)f2bf(hv[2]) | ((u32)f2bf(hv[3]) << 16);
        u32* dst = (u32*)&Abuf[(t + 1) & 1][0];
        *(uint2*)&dst[m * 64 + ((ws ^ m) << 2) + woff] = make_uint2(lo, hi);
        __syncthreads();
        const u16* src = &Abuf[(t + 1) & 1][0];
#pragma unroll
        for (int ks = 0; ks < 4; ++ks)
            a[ks] = *(const bf16x8*)&src[m * 128 + (((ks * 4 + quad) ^ m) << 3)];
#pragma unroll
        for (int j = 0; j < 4; ++j) g[j] = gn[j];
    }
}

// ---------------------------------------------------------------------------
// Readout: out[b,t,n,c] = mask ? OUTH_row . ro_W[c] + ro_b[c] : 0   (fp32 out)
// ---------------------------------------------------------------------------
__global__ __launch_bounds__(256) void k_readout(const float* __restrict__ OUTH,
                                                 const u16* __restrict__ roW,
                                                 const u16* __restrict__ rob,
                                                 const int* __restrict__ nnr,
                                                 float* __restrict__ out) {
    const int idx = blockIdx.x * 256 + threadIdx.x;
    const int btn = idx / C_, c = idx - btn * C_;
    const int bt = btn / N_, n = btn - bt * N_;
    const int b = bt / T_, t = bt - b * T_;
    const int nv = nnr[bt];
    float val = 0.0f;
    if (n < nv) {
        const float* hrow = OUTH + ((size_t)t * 192 + b * N_ + n) * 128;
        const uint2* w2 = (const uint2*)&roW[c * 128];
        float acc = bf2f(rob[c]);
#pragma unroll
        for (int k4 = 0; k4 < 32; ++k4) {
            const float4 h4 = *(const float4*)&hrow[k4 * 4];
            const uint2 ww = w2[k4];
            acc = fmaf(bf2f((u16)ww.x), h4.x,
                  fmaf(bf2f((u16)(ww.x >> 16)), h4.y,
                  fmaf(bf2f((u16)ww.y), h4.z,
                  fmaf(bf2f((u16)(ww.y >> 16)), h4.w, acc))));
        }
        val = acc;
    }
    out[idx] = val;
}

// ---------------------------------------------------------------------------
extern "C" void kernel_launch(void* const* d_in, const int* in_sizes, int n_in,
                              void* d_out, int out_size, void* d_ws, size_t ws_size,
                              hipStream_t stream) {
    const float* node = (const float*)d_in[0];
    const float* edge = (const float*)d_in[1];
    const int* nnr = (const int*)d_in[19];

    // Workspace layout (~62 MB)
    char* ws = (char*)d_ws;
    float* HN = (float*)ws;   ws += (size_t)BTN_ * D_ * 4;    // 3.15 MB
    u16* HNb = (u16*)ws;      ws += (size_t)BTN_ * D_ * 2;    // 1.57 MB
    float* XW = (float*)ws;   ws += (size_t)BTN_ * D_ * 4;    // 3.15 MB
    u16* MVb = (u16*)ws;      ws += (size_t)BTN_ * D_ * 2;    // 1.57 MB
    float* ADJ = (float*)ws;  ws += (size_t)BTVW_ * 4;        // 0.59 MB
    float* GI = (float*)ws;   ws += (size_t)BTN_ * 512 * 4;   // 12.58 MB (GI2 layout)
    u16* WThh = (u16*)ws;     ws += 65536 * 2;                // 0.13 MB (unused, kept)
    u16* ME = (u16*)ws;       ws += (size_t)BTVW_ * D_ * 2;   // 37.75 MB
    float* OUTH = XW;         // XW dead after last k_fused; same size

    // Weight slots (same 17-slot layout; the 7 big ones hold FRAGMENT-LINEAR
    // bf16; the 10 small ones canonical bf16) — all written by k_preproc.
    u16* cbase = (u16*)ws;
    const int cvtN17[17] = {16384, 128, 128, 1, 16384, 16384, 128,
                            49152, 49152, 384, 384, 65536, 65536, 512, 512, 768, 6};
    u16* cptr[17];
    {
        int off = 0;
        for (int i = 0; i < 17; ++i) {
            cptr[i] = cbase + off;
            off += (cvtN17[i] + 7) & ~7;
        }
    }
    PreArgs pa;
    pa.node = node; pa.HN = HN; pa.HNb = HNb;
    {
        const int din_idx[7] = {2, 6, 7, 9, 10, 13, 14};
        const int slot[7]    = {0, 4, 5, 7,  8, 11, 12};
        const int nelem[7]   = {16384, 16384, 16384, 49152, 49152, 65536, 65536};
        int cum = 0;
        for (int i = 0; i < 7; ++i) {
            pa.fsrc[i] = (const float*)d_in[din_idx[i]];
            pa.fdst[i] = cptr[slot[i]];
            pa.fstart[i] = cum;
            cum += nelem[i];
        }
        pa.fstart[7] = cum;             // 278528 = 1088 * 256
    }
    {
        const int din_idx[10] = {3, 4, 5, 8, 11, 12, 15, 16, 17, 18};
        const int slot[10]    = {1, 2, 3, 6,  9, 10, 13, 14, 15, 16};
        const int nelem[10]   = {128, 128, 1, 128, 384, 384, 512, 512, 768, 6};
        int cum = 0;
        for (int i = 0; i < 10; ++i) {
            pa.csrc[i] = d_in[din_idx[i]];
            pa.cdst[i] = cptr[slot[i]];
            pa.cstart[i] = cum;
            cum += nelem[i];
        }
        pa.cstart[10] = cum;            // 2951
    }
    u16* fW1 = cptr[0];  u16* cb1 = cptr[1];  u16* cW2 = cptr[2];  u16* cb2 = cptr[3];
    u16* fWh = cptr[4];  u16* fWe = cptr[5];  u16* cmb = cptr[6];
    u16* fgWih = cptr[7]; u16* fgWhh = cptr[8]; u16* cgbih = cptr[9]; u16* cgbhh = cptr[10];
    u16* flsWih = cptr[11]; u16* flsWhh = cptr[12]; u16* clsbih = cptr[13]; u16* clsbhh = cptr[14];
    u16* croW = cptr[15]; u16* crob = cptr[16];
    (void)WThh;

    k_preproc<<<1356, 256, 0, stream>>>(pa);
    k_prep<<<BT_ * 18, 128, 0, stream>>>(edge, fWe, fW1, cb1, cW2, cb2, nnr, ME, ADJ);
    for (int l = 0; l < P_; ++l) {
        k_xw<<<dim3(384, 4), 64, 0, stream>>>(HNb, fWh, nnr, XW);
        if (l < P_ - 1)
            k_fused<true><<<BTN_ / 2, 256, 0, stream>>>(ME, XW, cmb, fW1, cb1, cW2, cb2,
                                                        nnr, ADJ, MVb);
        else
            k_fused<false><<<BTN_ / 2, 256, 0, stream>>>(ME, XW, cmb, fW1, cb1, cW2, cb2,
                                                         nnr, ADJ, MVb);
        k_gruM<<<dim3(384, 4), 64, 0, stream>>>(MVb, HNb, HN, HNb, fgWih, fgWhh, cgbih, cgbhh, nnr);
    }
    k_gi<<<dim3(384, 8), 64, 0, stream>>>(HNb, flsWih, clsbih, clsbhh, GI);
    k_rec<<<12, 512, 0, stream>>>(GI, flsWhh, OUTH);
    k_readout<<<144, 256, 0, stream>>>(OUTH, croW, crob, nnr, (float*)d_out);
}